// Round 15
// baseline (250.794 us; speedup 1.0000x reference)
//
#include <hip/hip_runtime.h>
#include <hip/hip_bf16.h>

#define B_  2
#define S_  2048
#define M_  64
#define D_  1024
#define T_  2112      // M_ + S_
#define H_  16
#define HD_ 64
#define BT_ (B_*T_)   // 4224
#define NEGBIG (-1e9f)
#define LOG2E 1.44269504f

typedef float f32x4  __attribute__((ext_vector_type(4)));
typedef short short8 __attribute__((ext_vector_type(8)));
typedef unsigned short u16x4 __attribute__((ext_vector_type(4)));
typedef __bf16 bf16x8 __attribute__((ext_vector_type(8)));

typedef unsigned short TileBuf[2][128][64];   // 32 KB

static __device__ __forceinline__ unsigned short bf16_of(float f) {
  __hip_bfloat16 h = __float2bfloat16(f);
  return __builtin_bit_cast(unsigned short, h);
}

static __device__ __forceinline__ f32x4 mfma_bf16(short8 a, short8 b, f32x4 c) {
  return __builtin_amdgcn_mfma_f32_16x16x32_bf16(
      __builtin_bit_cast(bf16x8, a), __builtin_bit_cast(bf16x8, b), c, 0, 0, 0);
}

// async global->LDS, 16B per lane; lds base must be wave-uniform (lane adds l*16).
static __device__ __forceinline__ void gload16(const void* g, void* lds) {
  __builtin_amdgcn_global_load_lds(
      (const __attribute__((address_space(1))) unsigned int*)g,
      (__attribute__((address_space(3))) unsigned int*)lds, 16, 0, 0);
}

// ---------------- cast / concat kernels ----------------

__global__ void k_build_x(const float* __restrict__ tokens,
                          const float* __restrict__ memory,
                          unsigned short* __restrict__ xb) {
  for (int i = blockIdx.x * blockDim.x + threadIdx.x; i < BT_ * D_;
       i += gridDim.x * blockDim.x) {
    int b = i / (T_ * D_);
    int rem = i - b * (T_ * D_);
    int t = rem / D_;
    int d = rem - t * D_;
    float v = (t < M_) ? memory[((size_t)b * M_ + t) * D_ + d]
                       : tokens[((size_t)b * S_ + (t - M_)) * D_ + d];
    xb[i] = bf16_of(v);
  }
}

// casts: Wq,Wk,Wv -> contiguous Wqkvb (3x1M), Wo (1M), cell_W (4M), pool_q (64K scaled)
__global__ void k_cast_all(const float* __restrict__ Wq, const float* __restrict__ Wk,
                           const float* __restrict__ Wv, const float* __restrict__ Wo,
                           const float* __restrict__ cW, const float* __restrict__ pq,
                           unsigned short* __restrict__ Wqkvb, unsigned short* __restrict__ Wob,
                           unsigned short* __restrict__ cWb, unsigned short* __restrict__ pqb) {
  const int NW = D_ * D_;            // 1M
  const int NC = 4 * D_ * D_;        // 4M
  const int NP = M_ * D_;            // 64K
  const int total = 4 * NW + NC + NP;
  for (int i = blockIdx.x * blockDim.x + threadIdx.x; i < total;
       i += gridDim.x * blockDim.x) {
    if (i < 3 * NW) {
      int which = i >> 20, j = i & (NW - 1);
      const float* s = (which == 0) ? Wq : (which == 1) ? Wk : Wv;
      Wqkvb[i] = bf16_of(s[j]);
    } else if (i < 4 * NW) {
      int j = i - 3 * NW;
      Wob[j] = bf16_of(Wo[j]);
    } else if (i < 4 * NW + NC) {
      int j = i - 4 * NW;
      cWb[j] = bf16_of(cW[j]);
    } else {
      int j = i - 4 * NW - NC;
      pqb[j] = bf16_of(pq[j] * 0.03125f * LOG2E);   // D^-0.5, exp2-domain
    }
  }
}

// ---------------- 128x128 GEMM core: dbuf BK=64, counted vmcnt (T4) ----------------
__device__ __forceinline__ void gemm128_core(TileBuf& As, TileBuf& Bs,
                                             const unsigned short* __restrict__ A,
                                             const unsigned short* __restrict__ BT,
                                             int K, int m0, int n0,
                                             f32x4 acc[4][4]) {
  const int tid = threadIdx.x;
  const int w = tid >> 6, l = tid & 63;
  const int wr = w >> 1, wc = w & 1;
  const int lr = l & 15, lg = l >> 4;
  f32x4 z; z[0] = z[1] = z[2] = z[3] = 0.f;
#pragma unroll
  for (int i = 0; i < 4; i++)
#pragma unroll
    for (int j = 0; j < 4; j++) acc[i][j] = z;

  auto stage = [&](int buf, int k0) {
#pragma unroll
    for (int c = 0; c < 4; c++) {
      int rbase = c * 32 + w * 8;
      int rr = rbase + (l >> 3);
      int u = (l & 7) ^ (rr & 7);
      gload16(&A[(size_t)(m0 + rr) * K + k0 + u * 8], &As[buf][rbase][0]);
      gload16(&BT[(size_t)(n0 + rr) * K + k0 + u * 8], &Bs[buf][rbase][0]);
    }
  };

  stage(0, 0);
  int cur = 0;
  const int NK = K >> 6;
  for (int kt = 0; kt < NK; kt++) {
    if (kt + 1 < NK) {
      stage(cur ^ 1, (kt + 1) << 6);
      asm volatile("s_waitcnt vmcnt(8)" ::: "memory");
    } else {
      asm volatile("s_waitcnt vmcnt(0)" ::: "memory");
    }
    __builtin_amdgcn_s_barrier();

    short8 a[4][2], b[4][2];
#pragma unroll
    for (int i = 0; i < 4; i++) {
      int row = wr * 64 + i * 16 + lr;
      int sw = row & 7;
#pragma unroll
      for (int kk = 0; kk < 2; kk++)
        a[i][kk] = *(const short8*)&As[cur][row][(((kk << 2) | lg) ^ sw) * 8];
    }
#pragma unroll
    for (int j = 0; j < 4; j++) {
      int row = wc * 64 + j * 16 + lr;
      int sw = row & 7;
#pragma unroll
      for (int kk = 0; kk < 2; kk++)
        b[j][kk] = *(const short8*)&Bs[cur][row][(((kk << 2) | lg) ^ sw) * 8];
    }
    __builtin_amdgcn_s_setprio(1);
#pragma unroll
    for (int kk = 0; kk < 2; kk++)
#pragma unroll
      for (int i = 0; i < 4; i++)
#pragma unroll
        for (int j = 0; j < 4; j++)
          acc[i][j] = mfma_bf16(a[i][kk], b[j][kk], acc[i][j]);
    __builtin_amdgcn_s_setprio(0);

    __builtin_amdgcn_s_barrier();
    cur ^= 1;
  }
}

// ---------------- small 64x64 GEMM core (partial-K capable) ----------------
__device__ __forceinline__ void gemm_core(const unsigned short* __restrict__ A,
                                          const unsigned short* __restrict__ BT,
                                          int ldk, int Klen, int m0, int n0,
                                          f32x4 acc[4]) {
  __shared__ __align__(16) unsigned short As[64][40];
  __shared__ __align__(16) unsigned short Bs[64][40];
  const int tid = threadIdx.x;
  const int w = tid >> 6, l = tid & 63;
  const int sr = tid >> 2, sc = (tid & 3) * 8;
  f32x4 z; z[0] = z[1] = z[2] = z[3] = 0.f;
  acc[0] = acc[1] = acc[2] = acc[3] = z;
  for (int k0 = 0; k0 < Klen; k0 += 32) {
    __syncthreads();
    *(short8*)&As[sr][sc] = *(const short8*)&A[(size_t)(m0 + sr) * ldk + k0 + sc];
    *(short8*)&Bs[sr][sc] = *(const short8*)&BT[(size_t)(n0 + sr) * ldk + k0 + sc];
    __syncthreads();
    short8 a = *(const short8*)&As[w * 16 + (l & 15)][(l >> 4) * 8];
#pragma unroll
    for (int n = 0; n < 4; n++) {
      short8 b = *(const short8*)&Bs[n * 16 + (l & 15)][(l >> 4) * 8];
      acc[n] = mfma_bf16(a, b, acc[n]);
    }
  }
}

// ---------------- Q/K projection (128-tile) ----------------
__global__ __launch_bounds__(256) void k_qk(
    const unsigned short* __restrict__ xb, const unsigned short* __restrict__ Wqkvb,
    const float* __restrict__ bq, const float* __restrict__ bk,
    unsigned short* __restrict__ qg, unsigned short* __restrict__ kg) {
  __shared__ __align__(16) TileBuf As;
  __shared__ __align__(16) TileBuf Bs;
  const int which = blockIdx.x >> 3;
  const unsigned short* W = Wqkvb + (size_t)which * D_ * D_;
  const float* bias = (which == 0) ? bq : bk;
  f32x4 acc[4][4];
  const int m0 = blockIdx.y * 128, n0 = (blockIdx.x & 7) * 128;
  gemm128_core(As, Bs, xb, W, D_, m0, n0, acc);
  const int tid = threadIdx.x, w = tid >> 6, l = tid & 63;
  const int wr = w >> 1, wc = w & 1;
#pragma unroll
  for (int i = 0; i < 4; i++) {
#pragma unroll
    for (int j = 0; j < 4; j++) {
#pragma unroll
      for (int r = 0; r < 4; r++) {
        int m = m0 + wr * 64 + i * 16 + (l >> 4) * 4 + r;
        int c = n0 + wc * 64 + j * 16 + (l & 15);
        int b = (m >= T_) ? 1 : 0;
        int t = m - b * T_;
        int h = c >> 6, dh = c & 63;
        int bh = b * H_ + h;
        float v = acc[i][j][r] + bias[c];
        if (which == 0)
          qg[((size_t)bh * T_ + t) * HD_ + dh] = bf16_of(v * 0.125f * LOG2E);
        else
          kg[((size_t)bh * T_ + t) * HD_ + dh] = bf16_of(v);
      }
    }
  }
}

// ---------------- V projection (128-tile) + LDS-transposed coalesced store ----------------
__global__ __launch_bounds__(256) void k_v(
    const unsigned short* __restrict__ xb, const unsigned short* __restrict__ Wqkvb,
    const float* __restrict__ bv, unsigned short* __restrict__ vTg) {
  __shared__ __align__(16) TileBuf As;
  __shared__ __align__(16) TileBuf Bs;
  f32x4 acc[4][4];
  const int m0 = blockIdx.y * 128, n0 = blockIdx.x * 128;
  gemm128_core(As, Bs, xb, Wqkvb + (size_t)2 * D_ * D_, D_, m0, n0, acc);
  const int tid = threadIdx.x, w = tid >> 6, l = tid & 63;
  const int wr = w >> 1, wc = w & 1, lr = l & 15, lg = l >> 4;
  unsigned short* tr = &As[0][0][0];          // 128(c) x 128(m) bf16 = 32 KB
#pragma unroll
  for (int i = 0; i < 4; i++) {
    int u = wr * 16 + i * 4 + lg;             // m-unit (4 consecutive m)
#pragma unroll
    for (int j = 0; j < 4; j++) {
      int c = wc * 64 + j * 16 + lr;
      u16x4 pk;
#pragma unroll
      for (int r = 0; r < 4; r++) pk[r] = bf16_of(acc[i][j][r] + bv[n0 + c]);
      *(u16x4*)&tr[(size_t)c * 128 + (u ^ (c & 15)) * 4] = pk;
    }
  }
  __syncthreads();
  const int c = tid >> 1, hs = tid & 1;
  const int cg = n0 + c;
  const int h = cg >> 6, dh = cg & 63;
#pragma unroll
  for (int q = 0; q < 8; q++) {
    int ch = hs * 8 + q;
    int uu0 = (2 * ch) ^ (c & 15), uu1 = (2 * ch + 1) ^ (c & 15);
    u16x4 a0 = *(const u16x4*)&tr[(size_t)c * 128 + uu0 * 4];
    u16x4 a1 = *(const u16x4*)&tr[(size_t)c * 128 + uu1 * 4];
    short8 ov;
#pragma unroll
    for (int k = 0; k < 4; k++) { ov[k] = a0[k]; ov[4 + k] = a1[k]; }
    int mg = m0 + ch * 8;
    int b = (mg >= T_) ? 1 : 0;
    int t = mg - b * T_;
    *(short8*)&vTg[((size_t)(b * H_ + h) * HD_ + dh) * T_ + t] = ov;
  }
}

// ---------------- fused attention: QBLK=128, 2 sub-tiles/wave, swizzled Ps ----------------
// grid: 544 blocks.  id = 8*((bh/8)*17 + qir) + bh%8; qt = qir==0 ? 0 : 17-qir
// (heavy tiles first: qt=0 and qt=16 are both 33 iters).
// Block = 4 waves x 32 q-rows = 128 q-rows; wave w rows [qt*128 + w*32 + mi*16 + lr).
// Ps[4][32][64] XOR-swizzled 4-elem units: h=(row&7)^((row>>3)&3), unit^=2h.
__global__ __launch_bounds__(256) void k_attn(
    const unsigned short* __restrict__ qg, const unsigned short* __restrict__ kg,
    const unsigned short* __restrict__ vTg, unsigned short* __restrict__ ctx) {
  const int id = blockIdx.x;
  const int xcd = id & 7;
  const int rem = id >> 3;
  const int g = rem / 17, qir = rem - g * 17;
  const int qt = (qir == 0) ? 0 : 17 - qir;
  const int bh = g * 8 + xcd;
  const int tid = threadIdx.x, w = tid >> 6, l = tid & 63;
  const int lr = l & 15, lg = l >> 4;
  __shared__ __align__(16) unsigned short Ks[2][64][64];
  __shared__ __align__(16) unsigned short Vs[2][64][64];
  __shared__ __align__(16) unsigned short Ps[4][32][64];

  const unsigned short* qb = qg + (size_t)bh * T_ * HD_;
  const unsigned short* kb = kg + (size_t)bh * T_ * HD_;
  const unsigned short* vb = vTg + (size_t)bh * HD_ * T_;

  // Q B-fragments: 2 sub-tiles of 16 q-rows each
  short8 aq[2][2];
#pragma unroll
  for (int mi = 0; mi < 2; mi++) {
    int tq = qt * 128 + w * 32 + mi * 16 + lr;
    int tqc = (tq < T_) ? tq : T_ - 1;
#pragma unroll
    for (int st = 0; st < 2; st++)
      aq[mi][st] = *(const short8*)&qb[(size_t)tqc * HD_ + st * 32 + lg * 8];
  }

  f32x4 zz; zz[0] = zz[1] = zz[2] = zz[3] = 0.f;
  f32x4 o[2][4];
#pragma unroll
  for (int mi = 0; mi < 2; mi++)
#pragma unroll
    for (int n = 0; n < 4; n++) o[mi][n] = zz;
  float mrun[2] = {-1e30f, -1e30f}, lrun[2] = {0.f, 0.f};

  const int nkt = (qt == 0) ? 33 : ((2 * qt + 2 < 33) ? 2 * qt + 2 : 33);
  const int qmin = (qt == 0) ? M_ : qt * 128;

  auto stage = [&](int buf, int kb2) {
#pragma unroll
    for (int i = 0; i < 2; i++) {
      int rr = w * 16 + i * 8 + (l >> 3);
      int swz = ((l & 7) ^ (rr & 7)) * 8;
      gload16(&kb[(size_t)(kb2 + rr) * HD_ + swz], &Ks[buf][w * 16 + i * 8][0]);
      gload16(&vb[(size_t)rr * T_ + kb2 + swz], &Vs[buf][w * 16 + i * 8][0]);
    }
  };

  stage(0, 0);
  __syncthreads();
  int cur = 0;

  for (int j = 0; j < nkt; j++) {
    const int kbase = j * 64;
    if (j + 1 < nkt) stage(cur ^ 1, kbase + 64);

    // K A-fragments from LDS (swizzled read); row = k-local = n*16+lr
    short8 bkf[2][4];
#pragma unroll
    for (int n = 0; n < 4; n++) {
      int row = n * 16 + lr;
      int sw = lr & 7;
#pragma unroll
      for (int st = 0; st < 2; st++)
        bkf[st][n] = *(const short8*)&Ks[cur][row][((st * 4 + lg) ^ sw) * 8];
    }
    // S^T = K * Q^T for both sub-tiles
    f32x4 s[2][4];
#pragma unroll
    for (int mi = 0; mi < 2; mi++)
#pragma unroll
      for (int n = 0; n < 4; n++) s[mi][n] = zz;
    __builtin_amdgcn_s_setprio(1);
#pragma unroll
    for (int st = 0; st < 2; st++)
#pragma unroll
      for (int mi = 0; mi < 2; mi++)
#pragma unroll
        for (int n = 0; n < 4; n++)
          s[mi][n] = mfma_bf16(bkf[st][n], aq[mi][st], s[mi][n]);
    __builtin_amdgcn_s_setprio(0);

    // causal mask (memory rows tq<M_ attend everywhere)
    if (kbase + 63 > qmin) {
#pragma unroll
      for (int mi = 0; mi < 2; mi++) {
        const int tq = qt * 128 + w * 32 + mi * 16 + lr;
#pragma unroll
        for (int n = 0; n < 4; n++)
#pragma unroll
          for (int r = 0; r < 4; r++) {
            int tk = kbase + n * 16 + lg * 4 + r;
            if (tq >= M_ && tk > tq) s[mi][n][r] = NEGBIG;
          }
      }
    }
    // row max per sub-tile: in-register + 2 shfl
    float pm[2];
#pragma unroll
    for (int mi = 0; mi < 2; mi++) {
      float p = s[mi][0][0];
#pragma unroll
      for (int n = 0; n < 4; n++)
#pragma unroll
        for (int r = 0; r < 4; r++) p = fmaxf(p, s[mi][n][r]);
      p = fmaxf(p, __shfl_xor(p, 16));
      p = fmaxf(p, __shfl_xor(p, 32));
      pm[mi] = p;
    }
    // defer-max
    bool need = (pm[0] > mrun[0] + 8.f) || (pm[1] > mrun[1] + 8.f);
    if (__any(need)) {
#pragma unroll
      for (int mi = 0; mi < 2; mi++) {
        float mn = fmaxf(mrun[mi], pm[mi]);
        float fac = exp2f(mrun[mi] - mn);
        mrun[mi] = mn;
        lrun[mi] *= fac;
        float fr[4];
#pragma unroll
        for (int r = 0; r < 4; r++) fr[r] = __shfl(fac, lg * 4 + r);
#pragma unroll
        for (int n = 0; n < 4; n++)
#pragma unroll
          for (int r = 0; r < 4; r++) o[mi][n][r] *= fr[r];
      }
    }
    // P = exp2(S - m); pack 4 -> swizzled u16x4 store
#pragma unroll
    for (int mi = 0; mi < 2; mi++) {
      const int row = mi * 16 + lr;
      const int hsw = (row & 7) ^ ((row >> 3) & 3);
#pragma unroll
      for (int n = 0; n < 4; n++) {
        u16x4 pk;
#pragma unroll
        for (int r = 0; r < 4; r++) {
          float p = exp2f(s[mi][n][r] - mrun[mi]);
          lrun[mi] += p;
          pk[r] = bf16_of(p);
        }
        *(u16x4*)&Ps[w][row][((n * 4 + lg) ^ (2 * hsw)) * 4] = pk;
      }
    }

    // V B-fragments, P A-fragments (swizzled b128), then PV
    short8 bvf[2][4];
#pragma unroll
    for (int n = 0; n < 4; n++) {
      int row = n * 16 + lr;
      int sw = lr & 7;
#pragma unroll
      for (int st = 0; st < 2; st++)
        bvf[st][n] = *(const short8*)&Vs[cur][row][((st * 4 + lg) ^ sw) * 8];
    }
    short8 ap[2][2];
#pragma unroll
    for (int mi = 0; mi < 2; mi++) {
      const int row = mi * 16 + lr;
      const int hsw = (row & 7) ^ ((row >> 3) & 3);
#pragma unroll
      for (int st = 0; st < 2; st++) {
        int ub = (st * 8 + lg * 2) ^ (2 * hsw);
        ap[mi][st] = *(const short8*)&Ps[w][row][ub * 4];
      }
    }
    __builtin_amdgcn_s_setprio(1);
#pragma unroll
    for (int st = 0; st < 2; st++)
#pragma unroll
      for (int mi = 0; mi < 2; mi++)
#pragma unroll
        for (int n = 0; n < 4; n++)
          o[mi][n] = mfma_bf16(ap[mi][st], bvf[st][n], o[mi][n]);
    __builtin_amdgcn_s_setprio(0);

    __syncthreads();
    cur ^= 1;
  }
  // epilogue
  const int b = bh >> 4, h = bh & 15;
#pragma unroll
  for (int mi = 0; mi < 2; mi++) {
    lrun[mi] += __shfl_xor(lrun[mi], 16);
    lrun[mi] += __shfl_xor(lrun[mi], 32);
    float linv[4];
#pragma unroll
    for (int r = 0; r < 4; r++) linv[r] = 1.f / __shfl(lrun[mi], lg * 4 + r);
#pragma unroll
    for (int n = 0; n < 4; n++)
#pragma unroll
      for (int r = 0; r < 4; r++) {
        int tq = qt * 128 + w * 32 + mi * 16 + lg * 4 + r;
        if (tq < T_) {
          float val = o[mi][n][r] * linv[r];
          ctx[((size_t)(b * T_ + tq)) * D_ + h * HD_ + n * 16 + lr] = bf16_of(val);
        }
      }
  }
}

// ---------------- output projection + residual + splits (128-tile) ----------------
__global__ __launch_bounds__(256) void k_out(
    const unsigned short* __restrict__ ctxb, const unsigned short* __restrict__ Wob,
    const float* __restrict__ bo, const float* __restrict__ tokens,
    const float* __restrict__ memory, float* __restrict__ out_tok,
    unsigned short* __restrict__ tokb, unsigned short* __restrict__ tokTb,
    float* __restrict__ memout, unsigned short* __restrict__ comb) {
  __shared__ __align__(16) TileBuf As;
  __shared__ __align__(16) TileBuf Bs;
  f32x4 acc[4][4];
  const int m0 = blockIdx.y * 128, n0 = blockIdx.x * 128;
  gemm128_core(As, Bs, ctxb, Wob, D_, m0, n0, acc);
  const int tid = threadIdx.x, w = tid >> 6, l = tid & 63;
  const int wr = w >> 1, wc = w & 1, lr = l & 15, lg = l >> 4;
  unsigned short* tr = &As[0][0][0];
#pragma unroll
  for (int i = 0; i < 4; i++) {
    int u = wr * 16 + i * 4 + lg;
#pragma unroll
    for (int j = 0; j < 4; j++) {
      int c = n0 + wc * 64 + j * 16 + lr;
      int cl = c - n0;
      u16x4 pk;
#pragma unroll
      for (int r = 0; r < 4; r++) {
        int m = m0 + wr * 64 + i * 16 + lg * 4 + r;
        int b = (m >= T_) ? 1 : 0;
        int t = m - b * T_;
        float xo = (t < M_) ? memory[((size_t)b * M_ + t) * D_ + c]
                            : tokens[((size_t)b * S_ + (t - M_)) * D_ + c];
        float val = acc[i][j][r] + bo[c] + xo;
        unsigned short vb16 = bf16_of(val);
        pk[r] = vb16;
        if (t < M_) {
          memout[((size_t)b * M_ + t) * D_ + c] = val;
          comb[((size_t)b * M_ + t) * (2 * D_) + c] = vb16;
        } else {
          size_t ti = (size_t)b * S_ + (t - M_);
          out_tok[ti * D_ + c] = val;
          tokb[ti * D_ + c] = vb16;
        }
      }
      *(u16x4*)&tr[(size_t)cl * 128 + (u ^ (cl & 15)) * 4] = pk;
    }
  }
  __syncthreads();
  const int cl = tid >> 1, hs = tid & 1;
  const int cg = n0 + cl;
#pragma unroll
  for (int q = 0; q < 8; q++) {
    int ch = hs * 8 + q;
    int mg = m0 + ch * 8;
    int b = (mg >= T_) ? 1 : 0;
    int t = mg - b * T_;
    if (t < M_) continue;
    int uu0 = (2 * ch) ^ (cl & 15), uu1 = (2 * ch + 1) ^ (cl & 15);
    u16x4 a0 = *(const u16x4*)&tr[(size_t)cl * 128 + uu0 * 4];
    u16x4 a1 = *(const u16x4*)&tr[(size_t)cl * 128 + uu1 * 4];
    short8 ov;
#pragma unroll
    for (int k = 0; k < 4; k++) { ov[k] = a0[k]; ov[4 + k] = a1[k]; }
    *(short8*)&tokTb[((size_t)b * D_ + cg) * S_ + (t - M_)] = ov;
  }
}

// ---------------- pool scores: split-K partials ----------------
__global__ __launch_bounds__(256) void k_pscore_part(
    const unsigned short* __restrict__ pqb, const unsigned short* __restrict__ tokb,
    float* __restrict__ pscp) {
  const int stile = blockIdx.x, ks = blockIdx.y, b = blockIdx.z;
  f32x4 acc[4];
  gemm_core(pqb + ks * 256, tokb + (size_t)b * S_ * D_ + ks * 256, D_, 256,
            0, stile * 64, acc);
  const int tid = threadIdx.x, w = tid >> 6, l = tid & 63;
  float* dst = pscp + ((size_t)(ks * B_ + b) * M_) * S_;
#pragma unroll
  for (int n = 0; n < 4; n++) {
#pragma unroll
    for (int r = 0; r < 4; r++) {
      int m = w * 16 + (l >> 4) * 4 + r;
      int s = stile * 64 + n * 16 + (l & 15);
      dst[(size_t)m * S_ + s] = acc[n][r];
    }
  }
}

// ---------------- pool softmax (sums 4 partials; exp2 domain) ----------------
__global__ __launch_bounds__(256) void k_psoftmax(const float* __restrict__ pscp,
                                                  unsigned short* __restrict__ pw) {
  const int row = blockIdx.x;          // b*64 + m
  const int b = row >> 6, m = row & 63;
  const int tid = threadIdx.x;
  float v[8];
  float mx = -1e30f;
#pragma unroll
  for (int i = 0; i < 8; i++) {
    int s = tid + i * 256;
    float acc = 0.f;
#pragma unroll
    for (int ks = 0; ks < 4; ks++)
      acc += pscp[((size_t)(ks * B_ + b) * M_ + m) * S_ + s];
    v[i] = acc;
    mx = fmaxf(mx, acc);
  }
#pragma unroll
  for (int off = 1; off < 64; off <<= 1) mx = fmaxf(mx, __shfl_xor(mx, off));
  __shared__ float rm[4], rs[4];
  if ((tid & 63) == 0) rm[tid >> 6] = mx;
  __syncthreads();
  mx = fmaxf(fmaxf(rm[0], rm[1]), fmaxf(rm[2], rm[3]));
  float sum = 0.f;
#pragma unroll
  for (int i = 0; i < 8; i++) {
    v[i] = exp2f(v[i] - mx);
    sum += v[i];
  }
#pragma unroll
  for (int off = 1; off < 64; off <<= 1) sum += __shfl_xor(sum, off);
  if ((tid & 63) == 0) rs[tid >> 6] = sum;
  __syncthreads();
  float inv = 1.f / (rs[0] + rs[1] + rs[2] + rs[3]);
#pragma unroll
  for (int i = 0; i < 8; i++)
    pw[(size_t)row * S_ + tid + i * 256] = bf16_of(v[i] * inv);
}

// ---------------- summary: split-K partials ----------------
__global__ __launch_bounds__(256) void k_summary_part(
    const unsigned short* __restrict__ pw, const unsigned short* __restrict__ tokTb,
    float* __restrict__ sump) {
  const int nt = blockIdx.x, ks = blockIdx.y, b = blockIdx.z;
  f32x4 acc[4];
  gemm_core(pw + (size_t)b * M_ * S_ + ks * 256,
            tokTb + (size_t)b * D_ * S_ + ks * 256, S_, 256, 0, nt * 64, acc);
  const int tid = threadIdx.x, w = tid >> 6, l = tid & 63;
  float* dst = sump + ((size_t)(ks * B_ + b) * M_) * D_;
#pragma unroll
  for (int n = 0; n < 4; n++) {
#pragma unroll
    for (int r = 0; r < 4; r++) {
      int m = w * 16 + (l >> 4) * 4 + r;
      int c = nt * 64 + n * 16 + (l & 15);
      dst[(size_t)m * D_ + c] = acc[n][r];
    }
  }
}

// combine summary partials -> comb[:, D_:]
__global__ void k_sumcomb(const float* __restrict__ sump,
                          unsigned short* __restrict__ comb) {
  int i = blockIdx.x * blockDim.x + threadIdx.x;
  if (i >= B_ * M_ * D_) return;
  int bm = i >> 10, c = i & 1023;
  int b = bm >> 6, m = bm & 63;
  float acc = 0.f;
#pragma unroll
  for (int ks = 0; ks < 8; ks++)
    acc += sump[((size_t)(ks * B_ + b) * M_ + m) * D_ + c];
  comb[((size_t)b * M_ + m) * (2 * D_) + D_ + c] = bf16_of(acc);
}

// ---------------- cell GEMM: split-K partials ----------------
__global__ __launch_bounds__(256) void k_cell_part(
    const unsigned short* __restrict__ comb, const unsigned short* __restrict__ cWb,
    float* __restrict__ cellp) {
  const int nt = blockIdx.x, mt = blockIdx.y, ks = blockIdx.z;
  f32x4 acc[4];
  gemm_core(comb + ks * 512, cWb + ks * 512, 2 * D_, 512, mt * 64, nt * 64, acc);
  const int tid = threadIdx.x, w = tid >> 6, l = tid & 63;
#pragma unroll
  for (int n = 0; n < 4; n++) {
#pragma unroll
    for (int r = 0; r < 4; r++) {
      int m = mt * 64 + w * 16 + (l >> 4) * 4 + r;
      int c = nt * 64 + n * 16 + (l & 15);
      cellp[((size_t)ks * (B_ * M_) + m) * (2 * D_) + c] = acc[n][r];
    }
  }
}

// ---------------- final gating (sums 4 cell partials + bias) ----------------
__global__ void k_newmem(const float* __restrict__ cellp,
                         const float* __restrict__ cb,
                         const float* __restrict__ memout,
                         float* __restrict__ out2) {
  int i = blockIdx.x * blockDim.x + threadIdx.x;
  if (i >= B_ * M_ * D_) return;
  int r = i >> 10, d = i & 1023;
  float gsum = cb[d], csum = cb[D_ + d];
#pragma unroll
  for (int ks = 0; ks < 4; ks++) {
    gsum += cellp[((size_t)ks * (B_ * M_) + r) * (2 * D_) + d];
    csum += cellp[((size_t)ks * (B_ * M_) + r) * (2 * D_) + D_ + d];
  }
  float sg = 1.f / (1.f + __expf(-gsum));
  float sc = 1.f / (1.f + __expf(-csum));
  out2[i] = memout[i] * sg + (1.f - sg) * (csum * sc);
}

// ---------------- launch ----------------
extern "C" void kernel_launch(void* const* d_in, const int* in_sizes, int n_in,
                              void* d_out, int out_size, void* d_ws, size_t ws_size,
                              hipStream_t stream) {
  const float* tokens = (const float*)d_in[0];
  const float* memory = (const float*)d_in[1];
  const float* Wq = (const float*)d_in[2];
  const float* bq = (const float*)d_in[3];
  const float* Wk = (const float*)d_in[4];
  const float* bk = (const float*)d_in[5];
  const float* Wv = (const float*)d_in[6];
  const float* bv = (const float*)d_in[7];
  const float* Wo = (const float*)d_in[8];
  const float* bo = (const float*)d_in[9];
  const float* pool_q = (const float*)d_in[10];
  const float* cell_W = (const float*)d_in[11];
  const float* cell_b = (const float*)d_in[12];

  size_t off = 0;
  auto alloc = [&](size_t bytes) -> void* {
    void* p = (char*)d_ws + off;
    off += (bytes + 255) & ~(size_t)255;
    return p;
  };
  unsigned short* xb    = (unsigned short*)alloc((size_t)BT_ * D_ * 2);
  unsigned short* Wqkvb = (unsigned short*)alloc((size_t)3 * D_ * D_ * 2);
  unsigned short* Wob   = (unsigned short*)alloc((size_t)D_ * D_ * 2);
  unsigned short* cWb   = (unsigned short*)alloc((size_t)(2 * D_) * (2 * D_) * 2);
  unsigned short* pqb   = (unsigned short*)alloc((size_t)M_ * D_ * 2);
  unsigned short* qg    = (unsigned short*)alloc((size_t)B_ * H_ * T_ * HD_ * 2);
  unsigned short* kg    = (unsigned short*)alloc((size_t)B_ * H_ * T_ * HD_ * 2);
  unsigned short* vTg   = (unsigned short*)alloc((size_t)B_ * H_ * HD_ * T_ * 2);
  unsigned short* ctxb  = (unsigned short*)alloc((size_t)BT_ * D_ * 2);
  unsigned short* tokb  = (unsigned short*)alloc((size_t)B_ * S_ * D_ * 2);
  unsigned short* tokTb = (unsigned short*)alloc((size_t)B_ * D_ * S_ * 2);
  float*          memout= (float*)alloc((size_t)B_ * M_ * D_ * 4);
  unsigned short* comb  = (unsigned short*)alloc((size_t)B_ * M_ * 2 * D_ * 2);
  unsigned short* pwt   = (unsigned short*)alloc((size_t)B_ * M_ * S_ * 2);
  float*          pscp  = (float*)alloc((size_t)4 * B_ * M_ * S_ * 4);
  float*          sump  = (float*)alloc((size_t)8 * B_ * M_ * D_ * 4);
  float*          cellp = (float*)alloc((size_t)4 * B_ * M_ * 2 * D_ * 4);

  float* out_tok = (float*)d_out;
  float* out_mem = out_tok + (size_t)B_ * S_ * D_;

  k_build_x<<<2048, 256, 0, stream>>>(tokens, memory, xb);
  k_cast_all<<<4096, 256, 0, stream>>>(Wq, Wk, Wv, Wo, cell_W, pool_q,
                                       Wqkvb, Wob, cWb, pqb);

  k_qk<<<dim3(16, 33), 256, 0, stream>>>(xb, Wqkvb, bq, bk, qg, kg);
  k_v<<<dim3(8, 33), 256, 0, stream>>>(xb, Wqkvb, bv, vTg);
  k_attn<<<544, 256, 0, stream>>>(qg, kg, vTg, ctxb);
  k_out<<<dim3(8, 33), 256, 0, stream>>>(ctxb, Wob, bo, tokens, memory, out_tok,
                                         tokb, tokTb, memout, comb);
  k_pscore_part<<<dim3(32, 4, 2), 256, 0, stream>>>(pqb, tokb, pscp);
  k_psoftmax<<<B_ * M_, 256, 0, stream>>>(pscp, pwt);
  k_summary_part<<<dim3(16, 8, 2), 256, 0, stream>>>(pwt, tokTb, sump);
  k_sumcomb<<<512, 256, 0, stream>>>(sump, comb);
  k_cell_part<<<dim3(32, 2, 4), 256, 0, stream>>>(comb, cWb, cellp);
  k_newmem<<<512, 256, 0, stream>>>(cellp, cell_b, memout, out_mem);
}

// Round 16
// 238.411 us; speedup vs baseline: 1.0519x; 1.0519x over previous
//
#include <hip/hip_runtime.h>
#include <hip/hip_bf16.h>

#define B_  2
#define S_  2048
#define M_  64
#define D_  1024
#define T_  2112      // M_ + S_
#define H_  16
#define HD_ 64
#define BT_ (B_*T_)   // 4224
#define NEGBIG (-1e9f)
#define LOG2E 1.44269504f

typedef float f32x4  __attribute__((ext_vector_type(4)));
typedef short short8 __attribute__((ext_vector_type(8)));
typedef unsigned short u16x4 __attribute__((ext_vector_type(4)));
typedef __bf16 bf16x8 __attribute__((ext_vector_type(8)));

typedef unsigned short TileBuf[2][128][64];   // 32 KB

static __device__ __forceinline__ unsigned short bf16_of(float f) {
  __hip_bfloat16 h = __float2bfloat16(f);
  return __builtin_bit_cast(unsigned short, h);
}

static __device__ __forceinline__ f32x4 mfma_bf16(short8 a, short8 b, f32x4 c) {
  return __builtin_amdgcn_mfma_f32_16x16x32_bf16(
      __builtin_bit_cast(bf16x8, a), __builtin_bit_cast(bf16x8, b), c, 0, 0, 0);
}

// async global->LDS, 16B per lane; lds base must be wave-uniform (lane adds l*16).
static __device__ __forceinline__ void gload16(const void* g, void* lds) {
  __builtin_amdgcn_global_load_lds(
      (const __attribute__((address_space(1))) unsigned int*)g,
      (__attribute__((address_space(3))) unsigned int*)lds, 16, 0, 0);
}

// ---------------- cast / concat kernels ----------------

__global__ void k_build_x(const float* __restrict__ tokens,
                          const float* __restrict__ memory,
                          unsigned short* __restrict__ xb) {
  for (int i = blockIdx.x * blockDim.x + threadIdx.x; i < BT_ * D_;
       i += gridDim.x * blockDim.x) {
    int b = i / (T_ * D_);
    int rem = i - b * (T_ * D_);
    int t = rem / D_;
    int d = rem - t * D_;
    float v = (t < M_) ? memory[((size_t)b * M_ + t) * D_ + d]
                       : tokens[((size_t)b * S_ + (t - M_)) * D_ + d];
    xb[i] = bf16_of(v);
  }
}

// casts: Wq,Wk,Wv -> contiguous Wqkvb (3x1M), Wo (1M), cell_W (4M), pool_q (64K scaled)
__global__ void k_cast_all(const float* __restrict__ Wq, const float* __restrict__ Wk,
                           const float* __restrict__ Wv, const float* __restrict__ Wo,
                           const float* __restrict__ cW, const float* __restrict__ pq,
                           unsigned short* __restrict__ Wqkvb, unsigned short* __restrict__ Wob,
                           unsigned short* __restrict__ cWb, unsigned short* __restrict__ pqb) {
  const int NW = D_ * D_;            // 1M
  const int NC = 4 * D_ * D_;        // 4M
  const int NP = M_ * D_;            // 64K
  const int total = 4 * NW + NC + NP;
  for (int i = blockIdx.x * blockDim.x + threadIdx.x; i < total;
       i += gridDim.x * blockDim.x) {
    if (i < 3 * NW) {
      int which = i >> 20, j = i & (NW - 1);
      const float* s = (which == 0) ? Wq : (which == 1) ? Wk : Wv;
      Wqkvb[i] = bf16_of(s[j]);
    } else if (i < 4 * NW) {
      int j = i - 3 * NW;
      Wob[j] = bf16_of(Wo[j]);
    } else if (i < 4 * NW + NC) {
      int j = i - 4 * NW;
      cWb[j] = bf16_of(cW[j]);
    } else {
      int j = i - 4 * NW - NC;
      pqb[j] = bf16_of(pq[j] * 0.03125f * LOG2E);   // D^-0.5, exp2-domain
    }
  }
}

// ---------------- 128x128 GEMM core: dbuf BK=64, counted vmcnt (T4) ----------------
__device__ __forceinline__ void gemm128_core(TileBuf& As, TileBuf& Bs,
                                             const unsigned short* __restrict__ A,
                                             const unsigned short* __restrict__ BT,
                                             int K, int m0, int n0,
                                             f32x4 acc[4][4]) {
  const int tid = threadIdx.x;
  const int w = tid >> 6, l = tid & 63;
  const int wr = w >> 1, wc = w & 1;
  const int lr = l & 15, lg = l >> 4;
  f32x4 z; z[0] = z[1] = z[2] = z[3] = 0.f;
#pragma unroll
  for (int i = 0; i < 4; i++)
#pragma unroll
    for (int j = 0; j < 4; j++) acc[i][j] = z;

  auto stage = [&](int buf, int k0) {
#pragma unroll
    for (int c = 0; c < 4; c++) {
      int rbase = c * 32 + w * 8;
      int rr = rbase + (l >> 3);
      int u = (l & 7) ^ (rr & 7);
      gload16(&A[(size_t)(m0 + rr) * K + k0 + u * 8], &As[buf][rbase][0]);
      gload16(&BT[(size_t)(n0 + rr) * K + k0 + u * 8], &Bs[buf][rbase][0]);
    }
  };

  stage(0, 0);
  int cur = 0;
  const int NK = K >> 6;
  for (int kt = 0; kt < NK; kt++) {
    if (kt + 1 < NK) {
      stage(cur ^ 1, (kt + 1) << 6);
      asm volatile("s_waitcnt vmcnt(8)" ::: "memory");
    } else {
      asm volatile("s_waitcnt vmcnt(0)" ::: "memory");
    }
    __builtin_amdgcn_s_barrier();

    short8 a[4][2], b[4][2];
#pragma unroll
    for (int i = 0; i < 4; i++) {
      int row = wr * 64 + i * 16 + lr;
      int sw = row & 7;
#pragma unroll
      for (int kk = 0; kk < 2; kk++)
        a[i][kk] = *(const short8*)&As[cur][row][(((kk << 2) | lg) ^ sw) * 8];
    }
#pragma unroll
    for (int j = 0; j < 4; j++) {
      int row = wc * 64 + j * 16 + lr;
      int sw = row & 7;
#pragma unroll
      for (int kk = 0; kk < 2; kk++)
        b[j][kk] = *(const short8*)&Bs[cur][row][(((kk << 2) | lg) ^ sw) * 8];
    }
    __builtin_amdgcn_s_setprio(1);
#pragma unroll
    for (int kk = 0; kk < 2; kk++)
#pragma unroll
      for (int i = 0; i < 4; i++)
#pragma unroll
        for (int j = 0; j < 4; j++)
          acc[i][j] = mfma_bf16(a[i][kk], b[j][kk], acc[i][j]);
    __builtin_amdgcn_s_setprio(0);

    __builtin_amdgcn_s_barrier();
    cur ^= 1;
  }
}

// ---------------- small 64x64 GEMM core (partial-K capable) ----------------
__device__ __forceinline__ void gemm_core(const unsigned short* __restrict__ A,
                                          const unsigned short* __restrict__ BT,
                                          int ldk, int Klen, int m0, int n0,
                                          f32x4 acc[4]) {
  __shared__ __align__(16) unsigned short As[64][40];
  __shared__ __align__(16) unsigned short Bs[64][40];
  const int tid = threadIdx.x;
  const int w = tid >> 6, l = tid & 63;
  const int sr = tid >> 2, sc = (tid & 3) * 8;
  f32x4 z; z[0] = z[1] = z[2] = z[3] = 0.f;
  acc[0] = acc[1] = acc[2] = acc[3] = z;
  for (int k0 = 0; k0 < Klen; k0 += 32) {
    __syncthreads();
    *(short8*)&As[sr][sc] = *(const short8*)&A[(size_t)(m0 + sr) * ldk + k0 + sc];
    *(short8*)&Bs[sr][sc] = *(const short8*)&BT[(size_t)(n0 + sr) * ldk + k0 + sc];
    __syncthreads();
    short8 a = *(const short8*)&As[w * 16 + (l & 15)][(l >> 4) * 8];
#pragma unroll
    for (int n = 0; n < 4; n++) {
      short8 b = *(const short8*)&Bs[n * 16 + (l & 15)][(l >> 4) * 8];
      acc[n] = mfma_bf16(a, b, acc[n]);
    }
  }
}

// ---------------- Q/K projection (128-tile) ----------------
__global__ __launch_bounds__(256) void k_qk(
    const unsigned short* __restrict__ xb, const unsigned short* __restrict__ Wqkvb,
    const float* __restrict__ bq, const float* __restrict__ bk,
    unsigned short* __restrict__ qg, unsigned short* __restrict__ kg) {
  __shared__ __align__(16) TileBuf As;
  __shared__ __align__(16) TileBuf Bs;
  const int which = blockIdx.x >> 3;
  const unsigned short* W = Wqkvb + (size_t)which * D_ * D_;
  const float* bias = (which == 0) ? bq : bk;
  f32x4 acc[4][4];
  const int m0 = blockIdx.y * 128, n0 = (blockIdx.x & 7) * 128;
  gemm128_core(As, Bs, xb, W, D_, m0, n0, acc);
  const int tid = threadIdx.x, w = tid >> 6, l = tid & 63;
  const int wr = w >> 1, wc = w & 1;
#pragma unroll
  for (int i = 0; i < 4; i++) {
#pragma unroll
    for (int j = 0; j < 4; j++) {
#pragma unroll
      for (int r = 0; r < 4; r++) {
        int m = m0 + wr * 64 + i * 16 + (l >> 4) * 4 + r;
        int c = n0 + wc * 64 + j * 16 + (l & 15);
        int b = (m >= T_) ? 1 : 0;
        int t = m - b * T_;
        int h = c >> 6, dh = c & 63;
        int bh = b * H_ + h;
        float v = acc[i][j][r] + bias[c];
        if (which == 0)
          qg[((size_t)bh * T_ + t) * HD_ + dh] = bf16_of(v * 0.125f * LOG2E);
        else
          kg[((size_t)bh * T_ + t) * HD_ + dh] = bf16_of(v);
      }
    }
  }
}

// ---------------- V projection (128-tile) + LDS-transposed coalesced store ----------------
__global__ __launch_bounds__(256) void k_v(
    const unsigned short* __restrict__ xb, const unsigned short* __restrict__ Wqkvb,
    const float* __restrict__ bv, unsigned short* __restrict__ vTg) {
  __shared__ __align__(16) TileBuf As;
  __shared__ __align__(16) TileBuf Bs;
  f32x4 acc[4][4];
  const int m0 = blockIdx.y * 128, n0 = blockIdx.x * 128;
  gemm128_core(As, Bs, xb, Wqkvb + (size_t)2 * D_ * D_, D_, m0, n0, acc);
  const int tid = threadIdx.x, w = tid >> 6, l = tid & 63;
  const int wr = w >> 1, wc = w & 1, lr = l & 15, lg = l >> 4;
  unsigned short* tr = &As[0][0][0];          // 128(c) x 128(m) bf16 = 32 KB
#pragma unroll
  for (int i = 0; i < 4; i++) {
    int u = wr * 16 + i * 4 + lg;             // m-unit (4 consecutive m)
#pragma unroll
    for (int j = 0; j < 4; j++) {
      int c = wc * 64 + j * 16 + lr;
      u16x4 pk;
#pragma unroll
      for (int r = 0; r < 4; r++) pk[r] = bf16_of(acc[i][j][r] + bv[n0 + c]);
      *(u16x4*)&tr[(size_t)c * 128 + (u ^ (c & 15)) * 4] = pk;
    }
  }
  __syncthreads();
  const int c = tid >> 1, hs = tid & 1;
  const int cg = n0 + c;
  const int h = cg >> 6, dh = cg & 63;
#pragma unroll
  for (int q = 0; q < 8; q++) {
    int ch = hs * 8 + q;
    int uu0 = (2 * ch) ^ (c & 15), uu1 = (2 * ch + 1) ^ (c & 15);
    u16x4 a0 = *(const u16x4*)&tr[(size_t)c * 128 + uu0 * 4];
    u16x4 a1 = *(const u16x4*)&tr[(size_t)c * 128 + uu1 * 4];
    short8 ov;
#pragma unroll
    for (int k = 0; k < 4; k++) { ov[k] = a0[k]; ov[4 + k] = a1[k]; }
    int mg = m0 + ch * 8;
    int b = (mg >= T_) ? 1 : 0;
    int t = mg - b * T_;
    *(short8*)&vTg[((size_t)(b * H_ + h) * HD_ + dh) * T_ + t] = ov;
  }
}

// ---------------- fused attention: swapped-operand QK^T, lane-local softmax ----------------
// grid: 1056 blocks.  id = 8*((bh/8)*33 + qtr) + bh%8; qt = qtr==0 ? 0 : 33-qtr
// (bh-group -> XCD, heavy tiles first INCLUDING qt=0).
// Block = 4 waves, 64 q-rows; wave w owns rows [qt*64 + w*16, +16).
// Ps[4][16][64] (LDS total 40960 = 160KB/4 -> 4 blocks/CU); 8-elem-unit XOR
// swizzle u8^=(lr&7): write 2 u16x4/row-n, read 1 b128/st.
__global__ __launch_bounds__(256) void k_attn(
    const unsigned short* __restrict__ qg, const unsigned short* __restrict__ kg,
    const unsigned short* __restrict__ vTg, unsigned short* __restrict__ ctx) {
  const int id = blockIdx.x;
  const int xcd = id & 7;
  const int rem = id >> 3;
  const int g = rem / 33, qtr = rem - g * 33;
  const int qt = (qtr == 0) ? 0 : 33 - qtr;
  const int bh = g * 8 + xcd;
  const int tid = threadIdx.x, w = tid >> 6, l = tid & 63;
  const int lr = l & 15, lg = l >> 4;
  __shared__ __align__(16) unsigned short Ks[2][64][64];
  __shared__ __align__(16) unsigned short Vs[2][64][64];
  __shared__ __align__(16) unsigned short Ps[4][16][64];

  const unsigned short* qb = qg + (size_t)bh * T_ * HD_;
  const unsigned short* kb = kg + (size_t)bh * T_ * HD_;
  const unsigned short* vb = vTg + (size_t)bh * HD_ * T_;

  short8 aq[2];
  const int qrow = qt * 64 + w * 16 + lr;
#pragma unroll
  for (int st = 0; st < 2; st++)
    aq[st] = *(const short8*)&qb[(size_t)qrow * HD_ + st * 32 + lg * 8];

  f32x4 zz; zz[0] = zz[1] = zz[2] = zz[3] = 0.f;
  f32x4 o[4];
  o[0] = o[1] = o[2] = o[3] = zz;
  float mrun = -1e30f, lrun = 0.f;   // lane-scalar state for q-row (w*16+lr)

  const int nkt = (qt == 0) ? 33 : qt + 1;

  auto stage = [&](int buf, int kb2) {
#pragma unroll
    for (int i = 0; i < 2; i++) {
      int rr = w * 16 + i * 8 + (l >> 3);
      int swz = ((l & 7) ^ (rr & 7)) * 8;
      gload16(&kb[(size_t)(kb2 + rr) * HD_ + swz], &Ks[buf][w * 16 + i * 8][0]);
      gload16(&vb[(size_t)rr * T_ + kb2 + swz], &Vs[buf][w * 16 + i * 8][0]);
    }
  };

  stage(0, 0);
  __syncthreads();
  int cur = 0;

  for (int j = 0; j < nkt; j++) {
    const int kbase = j * 64;
    if (j + 1 < nkt) stage(cur ^ 1, kbase + 64);

    short8 bkf[2][4];
#pragma unroll
    for (int n = 0; n < 4; n++) {
      int row = n * 16 + lr;
      int sw = lr & 7;
#pragma unroll
      for (int st = 0; st < 2; st++)
        bkf[st][n] = *(const short8*)&Ks[cur][row][((st * 4 + lg) ^ sw) * 8];
    }
    // S^T = K * Q^T : s[n][r] = S[k = kbase + n*16 + lg*4 + r][q-row = lr]
    f32x4 s[4];
    s[0] = s[1] = s[2] = s[3] = zz;
    __builtin_amdgcn_s_setprio(1);
#pragma unroll
    for (int st = 0; st < 2; st++)
#pragma unroll
      for (int n = 0; n < 4; n++)
        s[n] = mfma_bf16(bkf[st][n], aq[st], s[n]);
    __builtin_amdgcn_s_setprio(0);

    if (qt > 0 && j == qt) {
      const int tql = w * 16 + lr;
#pragma unroll
      for (int n = 0; n < 4; n++)
#pragma unroll
        for (int r = 0; r < 4; r++) {
          int tkl = n * 16 + lg * 4 + r;
          if (tkl > tql) s[n][r] = NEGBIG;
        }
    }
    float pm = s[0][0];
#pragma unroll
    for (int n = 0; n < 4; n++)
#pragma unroll
      for (int r = 0; r < 4; r++) pm = fmaxf(pm, s[n][r]);
    pm = fmaxf(pm, __shfl_xor(pm, 16));
    pm = fmaxf(pm, __shfl_xor(pm, 32));

    if (__any(pm > mrun + 8.f)) {
      float mn = fmaxf(mrun, pm);
      float fac = exp2f(mrun - mn);
      mrun = mn;
      lrun *= fac;
      float fr[4];
#pragma unroll
      for (int r = 0; r < 4; r++) fr[r] = __shfl(fac, lg * 4 + r);
#pragma unroll
      for (int n = 0; n < 4; n++)
#pragma unroll
        for (int r = 0; r < 4; r++) o[n][r] *= fr[r];
    }
    // P = exp2(S - m); pack 4 k-values -> swizzled b64 store
    // elem offset = ((u>>1)^(lr&7))*8 + (u&1)*4, u = n*4+lg
#pragma unroll
    for (int n = 0; n < 4; n++) {
      u16x4 pk;
#pragma unroll
      for (int r = 0; r < 4; r++) {
        float p = exp2f(s[n][r] - mrun);
        lrun += p;
        pk[r] = bf16_of(p);
      }
      int u = n * 4 + lg;
      int off = (((u >> 1) ^ (lr & 7)) << 3) + ((u & 1) << 2);
      *(u16x4*)&Ps[w][lr][off] = pk;
    }

    short8 bvf[2][4];
#pragma unroll
    for (int n = 0; n < 4; n++) {
      int row = n * 16 + lr;
      int sw = lr & 7;
#pragma unroll
      for (int st = 0; st < 2; st++)
        bvf[st][n] = *(const short8*)&Vs[cur][row][((st * 4 + lg) ^ sw) * 8];
    }
    short8 ap[2];
#pragma unroll
    for (int st = 0; st < 2; st++)
      ap[st] = *(const short8*)&Ps[w][lr][(((st * 4 + lg) ^ (lr & 7)) << 3)];
    __builtin_amdgcn_s_setprio(1);
#pragma unroll
    for (int st = 0; st < 2; st++)
#pragma unroll
      for (int n = 0; n < 4; n++)
        o[n] = mfma_bf16(ap[st], bvf[st][n], o[n]);
    __builtin_amdgcn_s_setprio(0);

    __syncthreads();
    cur ^= 1;
  }
  lrun += __shfl_xor(lrun, 16);
  lrun += __shfl_xor(lrun, 32);
  float linv[4];
#pragma unroll
  for (int r = 0; r < 4; r++) linv[r] = 1.f / __shfl(lrun, lg * 4 + r);

  const int b = bh >> 4, h = bh & 15;
#pragma unroll
  for (int n = 0; n < 4; n++)
#pragma unroll
    for (int r = 0; r < 4; r++) {
      int tq = qt * 64 + w * 16 + lg * 4 + r;
      float val = o[n][r] * linv[r];
      ctx[((size_t)(b * T_ + tq)) * D_ + h * HD_ + n * 16 + lr] = bf16_of(val);
    }
}

// ---------------- output projection + residual + splits (128-tile) ----------------
__global__ __launch_bounds__(256) void k_out(
    const unsigned short* __restrict__ ctxb, const unsigned short* __restrict__ Wob,
    const float* __restrict__ bo, const float* __restrict__ tokens,
    const float* __restrict__ memory, float* __restrict__ out_tok,
    unsigned short* __restrict__ tokb, unsigned short* __restrict__ tokTb,
    float* __restrict__ memout, unsigned short* __restrict__ comb) {
  __shared__ __align__(16) TileBuf As;
  __shared__ __align__(16) TileBuf Bs;
  f32x4 acc[4][4];
  const int m0 = blockIdx.y * 128, n0 = blockIdx.x * 128;
  gemm128_core(As, Bs, ctxb, Wob, D_, m0, n0, acc);
  const int tid = threadIdx.x, w = tid >> 6, l = tid & 63;
  const int wr = w >> 1, wc = w & 1, lr = l & 15, lg = l >> 4;
  unsigned short* tr = &As[0][0][0];
#pragma unroll
  for (int i = 0; i < 4; i++) {
    int u = wr * 16 + i * 4 + lg;
#pragma unroll
    for (int j = 0; j < 4; j++) {
      int c = n0 + wc * 64 + j * 16 + lr;
      int cl = c - n0;
      u16x4 pk;
#pragma unroll
      for (int r = 0; r < 4; r++) {
        int m = m0 + wr * 64 + i * 16 + lg * 4 + r;
        int b = (m >= T_) ? 1 : 0;
        int t = m - b * T_;
        float xo = (t < M_) ? memory[((size_t)b * M_ + t) * D_ + c]
                            : tokens[((size_t)b * S_ + (t - M_)) * D_ + c];
        float val = acc[i][j][r] + bo[c] + xo;
        unsigned short vb16 = bf16_of(val);
        pk[r] = vb16;
        if (t < M_) {
          memout[((size_t)b * M_ + t) * D_ + c] = val;
          comb[((size_t)b * M_ + t) * (2 * D_) + c] = vb16;
        } else {
          size_t ti = (size_t)b * S_ + (t - M_);
          out_tok[ti * D_ + c] = val;
          tokb[ti * D_ + c] = vb16;
        }
      }
      *(u16x4*)&tr[(size_t)cl * 128 + (u ^ (cl & 15)) * 4] = pk;
    }
  }
  __syncthreads();
  const int cl = tid >> 1, hs = tid & 1;
  const int cg = n0 + cl;
#pragma unroll
  for (int q = 0; q < 8; q++) {
    int ch = hs * 8 + q;
    int mg = m0 + ch * 8;
    int b = (mg >= T_) ? 1 : 0;
    int t = mg - b * T_;
    if (t < M_) continue;
    int uu0 = (2 * ch) ^ (cl & 15), uu1 = (2 * ch + 1) ^ (cl & 15);
    u16x4 a0 = *(const u16x4*)&tr[(size_t)cl * 128 + uu0 * 4];
    u16x4 a1 = *(const u16x4*)&tr[(size_t)cl * 128 + uu1 * 4];
    short8 ov;
#pragma unroll
    for (int k = 0; k < 4; k++) { ov[k] = a0[k]; ov[4 + k] = a1[k]; }
    *(short8*)&tokTb[((size_t)b * D_ + cg) * S_ + (t - M_)] = ov;
  }
}

// ---------------- pool scores: split-K partials ----------------
__global__ __launch_bounds__(256) void k_pscore_part(
    const unsigned short* __restrict__ pqb, const unsigned short* __restrict__ tokb,
    float* __restrict__ pscp) {
  const int stile = blockIdx.x, ks = blockIdx.y, b = blockIdx.z;
  f32x4 acc[4];
  gemm_core(pqb + ks * 256, tokb + (size_t)b * S_ * D_ + ks * 256, D_, 256,
            0, stile * 64, acc);
  const int tid = threadIdx.x, w = tid >> 6, l = tid & 63;
  float* dst = pscp + ((size_t)(ks * B_ + b) * M_) * S_;
#pragma unroll
  for (int n = 0; n < 4; n++) {
#pragma unroll
    for (int r = 0; r < 4; r++) {
      int m = w * 16 + (l >> 4) * 4 + r;
      int s = stile * 64 + n * 16 + (l & 15);
      dst[(size_t)m * S_ + s] = acc[n][r];
    }
  }
}

// ---------------- pool softmax (sums 4 partials; exp2 domain) ----------------
__global__ __launch_bounds__(256) void k_psoftmax(const float* __restrict__ pscp,
                                                  unsigned short* __restrict__ pw) {
  const int row = blockIdx.x;          // b*64 + m
  const int b = row >> 6, m = row & 63;
  const int tid = threadIdx.x;
  float v[8];
  float mx = -1e30f;
#pragma unroll
  for (int i = 0; i < 8; i++) {
    int s = tid + i * 256;
    float acc = 0.f;
#pragma unroll
    for (int ks = 0; ks < 4; ks++)
      acc += pscp[((size_t)(ks * B_ + b) * M_ + m) * S_ + s];
    v[i] = acc;
    mx = fmaxf(mx, acc);
  }
#pragma unroll
  for (int off = 1; off < 64; off <<= 1) mx = fmaxf(mx, __shfl_xor(mx, off));
  __shared__ float rm[4], rs[4];
  if ((tid & 63) == 0) rm[tid >> 6] = mx;
  __syncthreads();
  mx = fmaxf(fmaxf(rm[0], rm[1]), fmaxf(rm[2], rm[3]));
  float sum = 0.f;
#pragma unroll
  for (int i = 0; i < 8; i++) {
    v[i] = exp2f(v[i] - mx);
    sum += v[i];
  }
#pragma unroll
  for (int off = 1; off < 64; off <<= 1) sum += __shfl_xor(sum, off);
  if ((tid & 63) == 0) rs[tid >> 6] = sum;
  __syncthreads();
  float inv = 1.f / (rs[0] + rs[1] + rs[2] + rs[3]);
#pragma unroll
  for (int i = 0; i < 8; i++)
    pw[(size_t)row * S_ + tid + i * 256] = bf16_of(v[i] * inv);
}

// ---------------- summary: split-K partials ----------------
__global__ __launch_bounds__(256) void k_summary_part(
    const unsigned short* __restrict__ pw, const unsigned short* __restrict__ tokTb,
    float* __restrict__ sump) {
  const int nt = blockIdx.x, ks = blockIdx.y, b = blockIdx.z;
  f32x4 acc[4];
  gemm_core(pw + (size_t)b * M_ * S_ + ks * 256,
            tokTb + (size_t)b * D_ * S_ + ks * 256, S_, 256, 0, nt * 64, acc);
  const int tid = threadIdx.x, w = tid >> 6, l = tid & 63;
  float* dst = sump + ((size_t)(ks * B_ + b) * M_) * D_;
#pragma unroll
  for (int n = 0; n < 4; n++) {
#pragma unroll
    for (int r = 0; r < 4; r++) {
      int m = w * 16 + (l >> 4) * 4 + r;
      int c = nt * 64 + n * 16 + (l & 15);
      dst[(size_t)m * D_ + c] = acc[n][r];
    }
  }
}

// combine summary partials -> comb[:, D_:]
__global__ void k_sumcomb(const float* __restrict__ sump,
                          unsigned short* __restrict__ comb) {
  int i = blockIdx.x * blockDim.x + threadIdx.x;
  if (i >= B_ * M_ * D_) return;
  int bm = i >> 10, c = i & 1023;
  int b = bm >> 6, m = bm & 63;
  float acc = 0.f;
#pragma unroll
  for (int ks = 0; ks < 8; ks++)
    acc += sump[((size_t)(ks * B_ + b) * M_ + m) * D_ + c];
  comb[((size_t)b * M_ + m) * (2 * D_) + D_ + c] = bf16_of(acc);
}

// ---------------- cell GEMM: split-K partials ----------------
__global__ __launch_bounds__(256) void k_cell_part(
    const unsigned short* __restrict__ comb, const unsigned short* __restrict__ cWb,
    float* __restrict__ cellp) {
  const int nt = blockIdx.x, mt = blockIdx.y, ks = blockIdx.z;
  f32x4 acc[4];
  gemm_core(comb + ks * 512, cWb + ks * 512, 2 * D_, 512, mt * 64, nt * 64, acc);
  const int tid = threadIdx.x, w = tid >> 6, l = tid & 63;
#pragma unroll
  for (int n = 0; n < 4; n++) {
#pragma unroll
    for (int r = 0; r < 4; r++) {
      int m = mt * 64 + w * 16 + (l >> 4) * 4 + r;
      int c = nt * 64 + n * 16 + (l & 15);
      cellp[((size_t)ks * (B_ * M_) + m) * (2 * D_) + c] = acc[n][r];
    }
  }
}

// ---------------- final gating (sums 4 cell partials + bias) ----------------
__global__ void k_newmem(const float* __restrict__ cellp,
                         const float* __restrict__ cb,
                         const float* __restrict__ memout,
                         float* __restrict__ out2) {
  int i = blockIdx.x * blockDim.x + threadIdx.x;
  if (i >= B_ * M_ * D_) return;
  int r = i >> 10, d = i & 1023;
  float gsum = cb[d], csum = cb[D_ + d];
#pragma unroll
  for (int ks = 0; ks < 4; ks++) {
    gsum += cellp[((size_t)ks * (B_ * M_) + r) * (2 * D_) + d];
    csum += cellp[((size_t)ks * (B_ * M_) + r) * (2 * D_) + D_ + d];
  }
  float sg = 1.f / (1.f + __expf(-gsum));
  float sc = 1.f / (1.f + __expf(-csum));
  out2[i] = memout[i] * sg + (1.f - sg) * (csum * sc);
}

// ---------------- launch ----------------
extern "C" void kernel_launch(void* const* d_in, const int* in_sizes, int n_in,
                              void* d_out, int out_size, void* d_ws, size_t ws_size,
                              hipStream_t stream) {
  const float* tokens = (const float*)d_in[0];
  const float* memory = (const float*)d_in[1];
  const float* Wq = (const float*)d_in[2];
  const float* bq = (const float*)d_in[3];
  const float* Wk = (const float*)d_in[4];
  const float* bk = (const float*)d_in[5];
  const float* Wv = (const float*)d_in[6];
  const float* bv = (const float*)d_in[7];
  const float* Wo = (const float*)d_in[8];
  const float* bo = (const float*)d_in[9];
  const float* pool_q = (const float*)d_in[10];
  const float* cell_W = (const float*)d_in[11];
  const float* cell_b = (const float*)d_in[12];

  size_t off = 0;
  auto alloc = [&](size_t bytes) -> void* {
    void* p = (char*)d_ws + off;
    off += (bytes + 255) & ~(size_t)255;
    return p;
  };
  unsigned short* xb    = (unsigned short*)alloc((size_t)BT_ * D_ * 2);
  unsigned short* Wqkvb = (unsigned short*)alloc((size_t)3 * D_ * D_ * 2);
  unsigned short* Wob   = (unsigned short*)alloc((size_t)D_ * D_ * 2);
  unsigned short* cWb   = (unsigned short*)alloc((size_t)(2 * D_) * (2 * D_) * 2);
  unsigned short* pqb   = (unsigned short*)alloc((size_t)M_ * D_ * 2);
  unsigned short* qg    = (unsigned short*)alloc((size_t)B_ * H_ * T_ * HD_ * 2);
  unsigned short* kg    = (unsigned short*)alloc((size_t)B_ * H_ * T_ * HD_ * 2);
  unsigned short* vTg   = (unsigned short*)alloc((size_t)B_ * H_ * HD_ * T_ * 2);
  unsigned short* ctxb  = (unsigned short*)alloc((size_t)BT_ * D_ * 2);
  unsigned short* tokb  = (unsigned short*)alloc((size_t)B_ * S_ * D_ * 2);
  unsigned short* tokTb = (unsigned short*)alloc((size_t)B_ * D_ * S_ * 2);
  float*          memout= (float*)alloc((size_t)B_ * M_ * D_ * 4);
  unsigned short* comb  = (unsigned short*)alloc((size_t)B_ * M_ * 2 * D_ * 2);
  unsigned short* pwt   = (unsigned short*)alloc((size_t)B_ * M_ * S_ * 2);
  float*          pscp  = (float*)alloc((size_t)4 * B_ * M_ * S_ * 4);
  float*          sump  = (float*)alloc((size_t)8 * B_ * M_ * D_ * 4);
  float*          cellp = (float*)alloc((size_t)4 * B_ * M_ * 2 * D_ * 4);

  float* out_tok = (float*)d_out;
  float* out_mem = out_tok + (size_t)B_ * S_ * D_;

  k_build_x<<<2048, 256, 0, stream>>>(tokens, memory, xb);
  k_cast_all<<<4096, 256, 0, stream>>>(Wq, Wk, Wv, Wo, cell_W, pool_q,
                                       Wqkvb, Wob, cWb, pqb);

  k_qk<<<dim3(16, 33), 256, 0, stream>>>(xb, Wqkvb, bq, bk, qg, kg);
  k_v<<<dim3(8, 33), 256, 0, stream>>>(xb, Wqkvb, bv, vTg);
  k_attn<<<1056, 256, 0, stream>>>(qg, kg, vTg, ctxb);
  k_out<<<dim3(8, 33), 256, 0, stream>>>(ctxb, Wob, bo, tokens, memory, out_tok,
                                         tokb, tokTb, memout, comb);
  k_pscore_part<<<dim3(32, 4, 2), 256, 0, stream>>>(pqb, tokb, pscp);
  k_psoftmax<<<B_ * M_, 256, 0, stream>>>(pscp, pwt);
  k_summary_part<<<dim3(16, 8, 2), 256, 0, stream>>>(pwt, tokTb, sump);
  k_sumcomb<<<512, 256, 0, stream>>>(sump, comb);
  k_cell_part<<<dim3(32, 2, 4), 256, 0, stream>>>(comb, cWb, cellp);
  k_newmem<<<512, 256, 0, stream>>>(cellp, cell_b, memout, out_mem);
}

// Round 17
// 237.136 us; speedup vs baseline: 1.0576x; 1.0054x over previous
//
#include <hip/hip_runtime.h>
#include <hip/hip_bf16.h>

#define B_  2
#define S_  2048
#define M_  64
#define D_  1024
#define T_  2112      // M_ + S_
#define H_  16
#define HD_ 64
#define BT_ (B_*T_)   // 4224
#define NEGBIG (-1e9f)
#define LOG2E 1.44269504f

typedef float f32x4  __attribute__((ext_vector_type(4)));
typedef short short8 __attribute__((ext_vector_type(8)));
typedef unsigned short u16x4 __attribute__((ext_vector_type(4)));
typedef __bf16 bf16x8 __attribute__((ext_vector_type(8)));

static __device__ __forceinline__ unsigned short bf16_of(float f) {
  __hip_bfloat16 h = __float2bfloat16(f);
  return __builtin_bit_cast(unsigned short, h);
}

static __device__ __forceinline__ f32x4 mfma_bf16(short8 a, short8 b, f32x4 c) {
  return __builtin_amdgcn_mfma_f32_16x16x32_bf16(
      __builtin_bit_cast(bf16x8, a), __builtin_bit_cast(bf16x8, b), c, 0, 0, 0);
}

// async global->LDS, 16B per lane; lds base must be wave-uniform (lane adds l*16).
static __device__ __forceinline__ void gload16(const void* g, void* lds) {
  __builtin_amdgcn_global_load_lds(
      (const __attribute__((address_space(1))) unsigned int*)g,
      (__attribute__((address_space(3))) unsigned int*)lds, 16, 0, 0);
}

// ---------------- cast / concat kernels ----------------

__global__ void k_build_x(const float* __restrict__ tokens,
                          const float* __restrict__ memory,
                          unsigned short* __restrict__ xb) {
  for (int i = blockIdx.x * blockDim.x + threadIdx.x; i < BT_ * D_;
       i += gridDim.x * blockDim.x) {
    int b = i / (T_ * D_);
    int rem = i - b * (T_ * D_);
    int t = rem / D_;
    int d = rem - t * D_;
    float v = (t < M_) ? memory[((size_t)b * M_ + t) * D_ + d]
                       : tokens[((size_t)b * S_ + (t - M_)) * D_ + d];
    xb[i] = bf16_of(v);
  }
}

// casts: Wq,Wk,Wv -> contiguous Wqkvb (3x1M), Wo (1M), cell_W (4M), pool_q (64K scaled)
__global__ void k_cast_all(const float* __restrict__ Wq, const float* __restrict__ Wk,
                           const float* __restrict__ Wv, const float* __restrict__ Wo,
                           const float* __restrict__ cW, const float* __restrict__ pq,
                           unsigned short* __restrict__ Wqkvb, unsigned short* __restrict__ Wob,
                           unsigned short* __restrict__ cWb, unsigned short* __restrict__ pqb) {
  const int NW = D_ * D_;            // 1M
  const int NC = 4 * D_ * D_;        // 4M
  const int NP = M_ * D_;            // 64K
  const int total = 4 * NW + NC + NP;
  for (int i = blockIdx.x * blockDim.x + threadIdx.x; i < total;
       i += gridDim.x * blockDim.x) {
    if (i < 3 * NW) {
      int which = i >> 20, j = i & (NW - 1);
      const float* s = (which == 0) ? Wq : (which == 1) ? Wk : Wv;
      Wqkvb[i] = bf16_of(s[j]);
    } else if (i < 4 * NW) {
      int j = i - 3 * NW;
      Wob[j] = bf16_of(Wo[j]);
    } else if (i < 4 * NW + NC) {
      int j = i - 4 * NW;
      cWb[j] = bf16_of(cW[j]);
    } else {
      int j = i - 4 * NW - NC;
      pqb[j] = bf16_of(pq[j] * 0.03125f * LOG2E);   // D^-0.5, exp2-domain
    }
  }
}

// ---------------- 128x128 GEMM core: dbuf BK=64, counted vmcnt (T4) ----------------
__device__ __forceinline__ void gemm128_core(const unsigned short* __restrict__ A,
                                             const unsigned short* __restrict__ BT,
                                             int K, int m0, int n0,
                                             f32x4 acc[4][4]) {
  __shared__ __align__(16) unsigned short As[2][128][64];
  __shared__ __align__(16) unsigned short Bs[2][128][64];
  const int tid = threadIdx.x;
  const int w = tid >> 6, l = tid & 63;
  const int wr = w >> 1, wc = w & 1;
  const int lr = l & 15, lg = l >> 4;
  f32x4 z; z[0] = z[1] = z[2] = z[3] = 0.f;
#pragma unroll
  for (int i = 0; i < 4; i++)
#pragma unroll
    for (int j = 0; j < 4; j++) acc[i][j] = z;

  auto stage = [&](int buf, int k0) {
#pragma unroll
    for (int c = 0; c < 4; c++) {
      int rbase = c * 32 + w * 8;
      int rr = rbase + (l >> 3);
      int u = (l & 7) ^ (rr & 7);
      gload16(&A[(size_t)(m0 + rr) * K + k0 + u * 8], &As[buf][rbase][0]);
      gload16(&BT[(size_t)(n0 + rr) * K + k0 + u * 8], &Bs[buf][rbase][0]);
    }
  };

  stage(0, 0);
  int cur = 0;
  const int NK = K >> 6;
  for (int kt = 0; kt < NK; kt++) {
    if (kt + 1 < NK) {
      stage(cur ^ 1, (kt + 1) << 6);
      asm volatile("s_waitcnt vmcnt(8)" ::: "memory");
    } else {
      asm volatile("s_waitcnt vmcnt(0)" ::: "memory");
    }
    __builtin_amdgcn_s_barrier();

    short8 a[4][2], b[4][2];
#pragma unroll
    for (int i = 0; i < 4; i++) {
      int row = wr * 64 + i * 16 + lr;
      int sw = row & 7;
#pragma unroll
      for (int kk = 0; kk < 2; kk++)
        a[i][kk] = *(const short8*)&As[cur][row][(((kk << 2) | lg) ^ sw) * 8];
    }
#pragma unroll
    for (int j = 0; j < 4; j++) {
      int row = wc * 64 + j * 16 + lr;
      int sw = row & 7;
#pragma unroll
      for (int kk = 0; kk < 2; kk++)
        b[j][kk] = *(const short8*)&Bs[cur][row][(((kk << 2) | lg) ^ sw) * 8];
    }
    __builtin_amdgcn_s_setprio(1);
#pragma unroll
    for (int kk = 0; kk < 2; kk++)
#pragma unroll
      for (int i = 0; i < 4; i++)
#pragma unroll
        for (int j = 0; j < 4; j++)
          acc[i][j] = mfma_bf16(a[i][kk], b[j][kk], acc[i][j]);
    __builtin_amdgcn_s_setprio(0);

    __builtin_amdgcn_s_barrier();
    cur ^= 1;
  }
}

// ---------------- small 64x64 GEMM core (partial-K capable) ----------------
__device__ __forceinline__ void gemm_core(const unsigned short* __restrict__ A,
                                          const unsigned short* __restrict__ BT,
                                          int ldk, int Klen, int m0, int n0,
                                          f32x4 acc[4]) {
  __shared__ __align__(16) unsigned short As[64][40];
  __shared__ __align__(16) unsigned short Bs[64][40];
  const int tid = threadIdx.x;
  const int w = tid >> 6, l = tid & 63;
  const int sr = tid >> 2, sc = (tid & 3) * 8;
  f32x4 z; z[0] = z[1] = z[2] = z[3] = 0.f;
  acc[0] = acc[1] = acc[2] = acc[3] = z;
  for (int k0 = 0; k0 < Klen; k0 += 32) {
    __syncthreads();
    *(short8*)&As[sr][sc] = *(const short8*)&A[(size_t)(m0 + sr) * ldk + k0 + sc];
    *(short8*)&Bs[sr][sc] = *(const short8*)&BT[(size_t)(n0 + sr) * ldk + k0 + sc];
    __syncthreads();
    short8 a = *(const short8*)&As[w * 16 + (l & 15)][(l >> 4) * 8];
#pragma unroll
    for (int n = 0; n < 4; n++) {
      short8 b = *(const short8*)&Bs[n * 16 + (l & 15)][(l >> 4) * 8];
      acc[n] = mfma_bf16(a, b, acc[n]);
    }
  }
}

// ---------------- fused QKV projection (128-tile, single launch) ----------------
// grid: x = n-tile (24: 8 per Q/K/V), y = m-tile (33). which = bx>>3.
__global__ __launch_bounds__(256) void k_qkv(
    const unsigned short* __restrict__ xb, const unsigned short* __restrict__ Wqkvb,
    const float* __restrict__ bq, const float* __restrict__ bk,
    const float* __restrict__ bv, unsigned short* __restrict__ qg,
    unsigned short* __restrict__ kg, unsigned short* __restrict__ vTg) {
  const int which = blockIdx.x >> 3;
  const unsigned short* W = Wqkvb + (size_t)which * D_ * D_;
  const float* bias = (which == 0) ? bq : ((which == 1) ? bk : bv);
  f32x4 acc[4][4];
  const int m0 = blockIdx.y * 128, n0 = (blockIdx.x & 7) * 128;
  gemm128_core(xb, W, D_, m0, n0, acc);
  const int tid = threadIdx.x, w = tid >> 6, l = tid & 63;
  const int wr = w >> 1, wc = w & 1;
#pragma unroll
  for (int i = 0; i < 4; i++) {
#pragma unroll
    for (int j = 0; j < 4; j++) {
#pragma unroll
      for (int r = 0; r < 4; r++) {
        int m = m0 + wr * 64 + i * 16 + (l >> 4) * 4 + r;
        int c = n0 + wc * 64 + j * 16 + (l & 15);
        int b = (m >= T_) ? 1 : 0;           // B_=2: single boundary compare
        int t = m - b * T_;
        int h = c >> 6, dh = c & 63;
        int bh = b * H_ + h;
        float v = acc[i][j][r] + bias[c];
        if (which == 0)
          qg[((size_t)bh * T_ + t) * HD_ + dh] = bf16_of(v * 0.125f * LOG2E);
        else if (which == 1)
          kg[((size_t)bh * T_ + t) * HD_ + dh] = bf16_of(v);
        else
          vTg[((size_t)bh * HD_ + dh) * T_ + t] = bf16_of(v);
      }
    }
  }
}

// ---------------- fused attention: K dbuf + V single-buf, counted vmcnt ----------------
// grid: 1056 blocks.  id = 8*((bh/8)*33 + qtr) + bh%8; qt = qtr==0 ? 0 : 33-qtr.
// Block = 4 waves, 64 q-rows; wave w owns rows [qt*64 + w*16, +16).
// LDS = Ks[2][64][64](16K) + Vs[64][64](8K) + Ps[4][16][72](9K) = 33792 B -> 4 blocks/CU.
// Per iter: issue {V_j(2), K_{j+1}(2)} -> vmcnt(4) [K_j landed] -> bar -> QK+softmax+P
//           -> vmcnt(2) [V_j landed] -> bar -> PV -> bar.  K prefetch spans a full iter.
__global__ __launch_bounds__(256) void k_attn(
    const unsigned short* __restrict__ qg, const unsigned short* __restrict__ kg,
    const unsigned short* __restrict__ vTg, unsigned short* __restrict__ ctx) {
  const int id = blockIdx.x;
  const int xcd = id & 7;
  const int rem = id >> 3;
  const int g = rem / 33, qtr = rem - g * 33;
  const int qt = (qtr == 0) ? 0 : 33 - qtr;
  const int bh = g * 8 + xcd;
  const int tid = threadIdx.x, w = tid >> 6, l = tid & 63;
  const int lr = l & 15, lg = l >> 4;
  __shared__ __align__(16) unsigned short Ks[2][64][64];
  __shared__ __align__(16) unsigned short Vs[64][64];
  __shared__ __align__(16) unsigned short Ps[4][16][72];

  const unsigned short* qb = qg + (size_t)bh * T_ * HD_;
  const unsigned short* kb = kg + (size_t)bh * T_ * HD_;
  const unsigned short* vb = vTg + (size_t)bh * HD_ * T_;

  // Q B-fragment: row = lr = this wave's q-row, cols lg*8
  short8 aq[2];
  const int qrow = qt * 64 + w * 16 + lr;
#pragma unroll
  for (int st = 0; st < 2; st++)
    aq[st] = *(const short8*)&qb[(size_t)qrow * HD_ + st * 32 + lg * 8];

  f32x4 zz; zz[0] = zz[1] = zz[2] = zz[3] = 0.f;
  f32x4 o[4];
  o[0] = o[1] = o[2] = o[3] = zz;
  float mrun = -1e30f, lrun = 0.f;   // lane-scalar state for q-row (w*16+lr)

  const int nkt = (qt == 0) ? 33 : qt + 1;

  const int srow8 = w * 16 + (l >> 3);            // this thread's staging row
  const int ldrow8 = w * 16 + ((l >> 3) & ~0u);   // == srow8 base for lds
  auto stageK = [&](int buf, int kb2) {
#pragma unroll
    for (int i = 0; i < 2; i++) {
      int rr = srow8 + i * 8;
      int swz = ((l & 7) ^ (rr & 7)) * 8;
      gload16(&kb[(size_t)(kb2 + rr) * HD_ + swz], &Ks[buf][w * 16 + i * 8][0]);
    }
  };
  auto stageV = [&](int kb2) {
#pragma unroll
    for (int i = 0; i < 2; i++) {
      int rr = srow8 + i * 8;
      int swz = ((l & 7) ^ (rr & 7)) * 8;
      gload16(&vb[(size_t)rr * T_ + kb2 + swz], &Vs[w * 16 + i * 8][0]);
    }
  };

  stageK(0, 0);                     // prologue: K_0 in flight (2 loads)
  int cur = 0;

  for (int j = 0; j < nkt; j++) {
    const int kbase = j * 64;
    const bool more = (j + 1 < nkt);
    // issue V_j (older) then K_{j+1}
    stageV(kbase);
    if (more) stageK(cur ^ 1, kbase + 64);

    // wait K_j (oldest); leave V_j (+K_{j+1}) in flight
    if (more) asm volatile("s_waitcnt vmcnt(4)" ::: "memory");
    else      asm volatile("s_waitcnt vmcnt(2)" ::: "memory");
    __builtin_amdgcn_s_barrier();

    // K A-fragments from LDS (swizzled read); row = k-local = n*16+lr
    short8 bkf[2][4];
#pragma unroll
    for (int n = 0; n < 4; n++) {
      int row = n * 16 + lr;
      int sw = lr & 7;
#pragma unroll
      for (int st = 0; st < 2; st++)
        bkf[st][n] = *(const short8*)&Ks[cur][row][((st * 4 + lg) ^ sw) * 8];
    }
    // S^T = K * Q^T : s[n][r] = S[k = kbase + n*16 + lg*4 + r][q-row = lr]
    f32x4 s[4];
    s[0] = s[1] = s[2] = s[3] = zz;
    __builtin_amdgcn_s_setprio(1);
#pragma unroll
    for (int st = 0; st < 2; st++)
#pragma unroll
      for (int n = 0; n < 4; n++)
        s[n] = mfma_bf16(bkf[st][n], aq[st], s[n]);
    __builtin_amdgcn_s_setprio(0);

    // causal mask on diagonal tile (qt==0 is all memory rows: no mask)
    if (qt > 0 && j == qt) {
      const int tql = w * 16 + lr;
#pragma unroll
      for (int n = 0; n < 4; n++)
#pragma unroll
        for (int r = 0; r < 4; r++) {
          int tkl = n * 16 + lg * 4 + r;
          if (tkl > tql) s[n][r] = NEGBIG;
        }
    }
    // row max: in-register + 2 shfl
    float pm = s[0][0];
#pragma unroll
    for (int n = 0; n < 4; n++)
#pragma unroll
      for (int r = 0; r < 4; r++) pm = fmaxf(pm, s[n][r]);
    pm = fmaxf(pm, __shfl_xor(pm, 16));
    pm = fmaxf(pm, __shfl_xor(pm, 32));

    // defer-max (exp2 domain, THR=8)
    if (__any(pm > mrun + 8.f)) {
      float mn = fmaxf(mrun, pm);
      float fac = exp2f(mrun - mn);
      mrun = mn;
      lrun *= fac;
      float fr[4];
#pragma unroll
      for (int r = 0; r < 4; r++) fr[r] = __shfl(fac, lg * 4 + r);
#pragma unroll
      for (int n = 0; n < 4; n++)
#pragma unroll
        for (int r = 0; r < 4; r++) o[n][r] *= fr[r];
    }
    // P = exp2(S - m); lane-partial row sum; pack 4 k-values -> one b64 store
#pragma unroll
    for (int n = 0; n < 4; n++) {
      u16x4 pk;
#pragma unroll
      for (int r = 0; r < 4; r++) {
        float p = exp2f(s[n][r] - mrun);
        lrun += p;
        pk[r] = bf16_of(p);
      }
      *(u16x4*)&Ps[w][lr][n * 16 + lg * 4] = pk;
    }

    // wait V_j; leave K_{j+1} in flight
    if (more) asm volatile("s_waitcnt vmcnt(2)" ::: "memory");
    else      asm volatile("s_waitcnt vmcnt(0)" ::: "memory");
    __builtin_amdgcn_s_barrier();

    // V B-fragments from LDS (swizzled read), P A-fragments, then PV
    short8 bvf[2][4];
#pragma unroll
    for (int n = 0; n < 4; n++) {
      int row = n * 16 + lr;
      int sw = lr & 7;
#pragma unroll
      for (int st = 0; st < 2; st++)
        bvf[st][n] = *(const short8*)&Vs[row][((st * 4 + lg) ^ sw) * 8];
    }
    short8 ap[2];
#pragma unroll
    for (int st = 0; st < 2; st++)
      ap[st] = *(const short8*)&Ps[w][lr][st * 32 + lg * 8];
    __builtin_amdgcn_s_setprio(1);
#pragma unroll
    for (int st = 0; st < 2; st++)
#pragma unroll
      for (int n = 0; n < 4; n++)
        o[n] = mfma_bf16(ap[st], bvf[st][n], o[n]);
    __builtin_amdgcn_s_setprio(0);

    __builtin_amdgcn_s_barrier();   // all PV reads done before next Vs overwrite
    cur ^= 1;
  }
  // epilogue: reduce lane partials, redistribute to o-accumulator q-mapping
  lrun += __shfl_xor(lrun, 16);
  lrun += __shfl_xor(lrun, 32);
  float linv[4];
#pragma unroll
  for (int r = 0; r < 4; r++) linv[r] = 1.f / __shfl(lrun, lg * 4 + r);

  const int b = bh >> 4, h = bh & 15;
#pragma unroll
  for (int n = 0; n < 4; n++)
#pragma unroll
    for (int r = 0; r < 4; r++) {
      int tq = qt * 64 + w * 16 + lg * 4 + r;
      float val = o[n][r] * linv[r];
      ctx[((size_t)(b * T_ + tq)) * D_ + h * HD_ + n * 16 + lr] = bf16_of(val);
    }
}

// ---------------- output projection + residual + splits (128-tile) ----------------
__global__ __launch_bounds__(256) void k_out(
    const unsigned short* __restrict__ ctxb, const unsigned short* __restrict__ Wob,
    const float* __restrict__ bo, const float* __restrict__ tokens,
    const float* __restrict__ memory, float* __restrict__ out_tok,
    unsigned short* __restrict__ tokb, unsigned short* __restrict__ tokTb,
    float* __restrict__ memout, unsigned short* __restrict__ comb) {
  f32x4 acc[4][4];
  const int m0 = blockIdx.y * 128, n0 = blockIdx.x * 128;
  gemm128_core(ctxb, Wob, D_, m0, n0, acc);
  const int tid = threadIdx.x, w = tid >> 6, l = tid & 63;
  const int wr = w >> 1, wc = w & 1;
#pragma unroll
  for (int i = 0; i < 4; i++) {
#pragma unroll
    for (int j = 0; j < 4; j++) {
#pragma unroll
      for (int r = 0; r < 4; r++) {
        int m = m0 + wr * 64 + i * 16 + (l >> 4) * 4 + r;
        int c = n0 + wc * 64 + j * 16 + (l & 15);
        int b = (m >= T_) ? 1 : 0;
        int t = m - b * T_;
        float xo = (t < M_) ? memory[((size_t)b * M_ + t) * D_ + c]
                            : tokens[((size_t)b * S_ + (t - M_)) * D_ + c];
        float val = acc[i][j][r] + bo[c] + xo;
        if (t < M_) {
          memout[((size_t)b * M_ + t) * D_ + c] = val;
          comb[((size_t)b * M_ + t) * (2 * D_) + c] = bf16_of(val);
        } else {
          size_t ti = (size_t)b * S_ + (t - M_);
          out_tok[ti * D_ + c] = val;
          tokb[ti * D_ + c] = bf16_of(val);
          tokTb[((size_t)b * D_ + c) * S_ + (t - M_)] = bf16_of(val);
        }
      }
    }
  }
}

// ---------------- pool scores: split-K partials ----------------
__global__ __launch_bounds__(256) void k_pscore_part(
    const unsigned short* __restrict__ pqb, const unsigned short* __restrict__ tokb,
    float* __restrict__ pscp) {
  const int stile = blockIdx.x, ks = blockIdx.y, b = blockIdx.z;
  f32x4 acc[4];
  gemm_core(pqb + ks * 256, tokb + (size_t)b * S_ * D_ + ks * 256, D_, 256,
            0, stile * 64, acc);
  const int tid = threadIdx.x, w = tid >> 6, l = tid & 63;
  float* dst = pscp + ((size_t)(ks * B_ + b) * M_) * S_;
#pragma unroll
  for (int n = 0; n < 4; n++) {
#pragma unroll
    for (int r = 0; r < 4; r++) {
      int m = w * 16 + (l >> 4) * 4 + r;
      int s = stile * 64 + n * 16 + (l & 15);
      dst[(size_t)m * S_ + s] = acc[n][r];
    }
  }
}

// ---------------- pool softmax (sums 4 partials; exp2 domain) ----------------
__global__ __launch_bounds__(256) void k_psoftmax(const float* __restrict__ pscp,
                                                  unsigned short* __restrict__ pw) {
  const int row = blockIdx.x;          // b*64 + m
  const int b = row >> 6, m = row & 63;
  const int tid = threadIdx.x;
  float v[8];
  float mx = -1e30f;
#pragma unroll
  for (int i = 0; i < 8; i++) {
    int s = tid + i * 256;
    float acc = 0.f;
#pragma unroll
    for (int ks = 0; ks < 4; ks++)
      acc += pscp[((size_t)(ks * B_ + b) * M_ + m) * S_ + s];
    v[i] = acc;
    mx = fmaxf(mx, acc);
  }
#pragma unroll
  for (int off = 1; off < 64; off <<= 1) mx = fmaxf(mx, __shfl_xor(mx, off));
  __shared__ float rm[4], rs[4];
  if ((tid & 63) == 0) rm[tid >> 6] = mx;
  __syncthreads();
  mx = fmaxf(fmaxf(rm[0], rm[1]), fmaxf(rm[2], rm[3]));
  float sum = 0.f;
#pragma unroll
  for (int i = 0; i < 8; i++) {
    v[i] = exp2f(v[i] - mx);
    sum += v[i];
  }
#pragma unroll
  for (int off = 1; off < 64; off <<= 1) sum += __shfl_xor(sum, off);
  if ((tid & 63) == 0) rs[tid >> 6] = sum;
  __syncthreads();
  float inv = 1.f / (rs[0] + rs[1] + rs[2] + rs[3]);
#pragma unroll
  for (int i = 0; i < 8; i++)
    pw[(size_t)row * S_ + tid + i * 256] = bf16_of(v[i] * inv);
}

// ---------------- summary: split-K partials ----------------
__global__ __launch_bounds__(256) void k_summary_part(
    const unsigned short* __restrict__ pw, const unsigned short* __restrict__ tokTb,
    float* __restrict__ sump) {
  const int nt = blockIdx.x, ks = blockIdx.y, b = blockIdx.z;
  f32x4 acc[4];
  gemm_core(pw + (size_t)b * M_ * S_ + ks * 256,
            tokTb + (size_t)b * D_ * S_ + ks * 256, S_, 256, 0, nt * 64, acc);
  const int tid = threadIdx.x, w = tid >> 6, l = tid & 63;
  float* dst = sump + ((size_t)(ks * B_ + b) * M_) * D_;
#pragma unroll
  for (int n = 0; n < 4; n++) {
#pragma unroll
    for (int r = 0; r < 4; r++) {
      int m = w * 16 + (l >> 4) * 4 + r;
      int c = nt * 64 + n * 16 + (l & 15);
      dst[(size_t)m * D_ + c] = acc[n][r];
    }
  }
}

// combine summary partials -> comb[:, D_:]
__global__ void k_sumcomb(const float* __restrict__ sump,
                          unsigned short* __restrict__ comb) {
  int i = blockIdx.x * blockDim.x + threadIdx.x;
  if (i >= B_ * M_ * D_) return;
  int bm = i >> 10, c = i & 1023;
  int b = bm >> 6, m = bm & 63;
  float acc = 0.f;
#pragma unroll
  for (int ks = 0; ks < 8; ks++)
    acc += sump[((size_t)(ks * B_ + b) * M_ + m) * D_ + c];
  comb[((size_t)b * M_ + m) * (2 * D_) + D_ + c] = bf16_of(acc);
}

// ---------------- cell GEMM: split-K partials ----------------
__global__ __launch_bounds__(256) void k_cell_part(
    const unsigned short* __restrict__ comb, const unsigned short* __restrict__ cWb,
    float* __restrict__ cellp) {
  const int nt = blockIdx.x, mt = blockIdx.y, ks = blockIdx.z;
  f32x4 acc[4];
  gemm_core(comb + ks * 512, cWb + ks * 512, 2 * D_, 512, mt * 64, nt * 64, acc);
  const int tid = threadIdx.x, w = tid >> 6, l = tid & 63;
#pragma unroll
  for (int n = 0; n < 4; n++) {
#pragma unroll
    for (int r = 0; r < 4; r++) {
      int m = mt * 64 + w * 16 + (l >> 4) * 4 + r;
      int c = nt * 64 + n * 16 + (l & 15);
      cellp[((size_t)ks * (B_ * M_) + m) * (2 * D_) + c] = acc[n][r];
    }
  }
}

// ---------------- final gating (sums 4 cell partials + bias) ----------------
__global__ void k_newmem(const float* __restrict__ cellp,
                         const float* __restrict__ cb,
                         const float* __restrict__ memout,
                         float* __restrict__ out2) {
  int i = blockIdx.x * blockDim.x + threadIdx.x;
  if (i >= B_ * M_ * D_) return;
  int r = i >> 10, d = i & 1023;
  float gsum = cb[d], csum = cb[D_ + d];
#pragma unroll
  for (int ks = 0; ks < 4; ks++) {
    gsum += cellp[((size_t)ks * (B_ * M_) + r) * (2 * D_) + d];
    csum += cellp[((size_t)ks * (B_ * M_) + r) * (2 * D_) + D_ + d];
  }
  float sg = 1.f / (1.f + __expf(-gsum));
  float sc = 1.f / (1.f + __expf(-csum));
  out2[i] = memout[i] * sg + (1.f - sg) * (csum * sc);
}

// ---------------- launch ----------------
extern "C" void kernel_launch(void* const* d_in, const int* in_sizes, int n_in,
                              void* d_out, int out_size, void* d_ws, size_t ws_size,
                              hipStream_t stream) {
  const float* tokens = (const float*)d_in[0];
  const float* memory = (const float*)d_in[1];
  const float* Wq = (const float*)d_in[2];
  const float* bq = (const float*)d_in[3];
  const float* Wk = (const float*)d_in[4];
  const float* bk = (const float*)d_in[5];
  const float* Wv = (const float*)d_in[6];
  const float* bv = (const float*)d_in[7];
  const float* Wo = (const float*)d_in[8];
  const float* bo = (const float*)d_in[9];
  const float* pool_q = (const float*)d_in[10];
  const float* cell_W = (const float*)d_in[11];
  const float* cell_b = (const float*)d_in[12];

  size_t off = 0;
  auto alloc = [&](size_t bytes) -> void* {
    void* p = (char*)d_ws + off;
    off += (bytes + 255) & ~(size_t)255;
    return p;
  };
  unsigned short* xb    = (unsigned short*)alloc((size_t)BT_ * D_ * 2);
  unsigned short* Wqkvb = (unsigned short*)alloc((size_t)3 * D_ * D_ * 2);
  unsigned short* Wob   = (unsigned short*)alloc((size_t)D_ * D_ * 2);
  unsigned short* cWb   = (unsigned short*)alloc((size_t)(2 * D_) * (2 * D_) * 2);
  unsigned short* pqb   = (unsigned short*)alloc((size_t)M_ * D_ * 2);
  unsigned short* qg    = (unsigned short*)alloc((size_t)B_ * H_ * T_ * HD_ * 2);
  unsigned short* kg    = (unsigned short*)alloc((size_t)B_ * H_ * T_ * HD_ * 2);
  unsigned short* vTg   = (unsigned short*)alloc((size_t)B_ * H_ * HD_ * T_ * 2);
  unsigned short* ctxb  = (unsigned short*)alloc((size_t)BT_ * D_ * 2);
  unsigned short* tokb  = (unsigned short*)alloc((size_t)B_ * S_ * D_ * 2);
  unsigned short* tokTb = (unsigned short*)alloc((size_t)B_ * D_ * S_ * 2);
  float*          memout= (float*)alloc((size_t)B_ * M_ * D_ * 4);
  unsigned short* comb  = (unsigned short*)alloc((size_t)B_ * M_ * 2 * D_ * 2);
  unsigned short* pwt   = (unsigned short*)alloc((size_t)B_ * M_ * S_ * 2);
  float*          pscp  = (float*)alloc((size_t)4 * B_ * M_ * S_ * 4);
  float*          sump  = (float*)alloc((size_t)8 * B_ * M_ * D_ * 4);
  float*          cellp = (float*)alloc((size_t)4 * B_ * M_ * 2 * D_ * 4);

  float* out_tok = (float*)d_out;
  float* out_mem = out_tok + (size_t)B_ * S_ * D_;

  k_build_x<<<2048, 256, 0, stream>>>(tokens, memory, xb);
  k_cast_all<<<4096, 256, 0, stream>>>(Wq, Wk, Wv, Wo, cell_W, pool_q,
                                       Wqkvb, Wob, cWb, pqb);

  k_qkv<<<dim3(24, 33), 256, 0, stream>>>(xb, Wqkvb, bq, bk, bv, qg, kg, vTg);
  k_attn<<<1056, 256, 0, stream>>>(qg, kg, vTg, ctxb);
  k_out<<<dim3(8, 33), 256, 0, stream>>>(ctxb, Wob, bo, tokens, memory, out_tok,
                                         tokb, tokTb, memout, comb);
  k_pscore_part<<<dim3(32, 4, 2), 256, 0, stream>>>(pqb, tokb, pscp);
  k_psoftmax<<<B_ * M_, 256, 0, stream>>>(pscp, pwt);
  k_summary_part<<<dim3(16, 8, 2), 256, 0, stream>>>(pwt, tokTb, sump);
  k_sumcomb<<<512, 256, 0, stream>>>(sump, comb);
  k_cell_part<<<dim3(32, 2, 4), 256, 0, stream>>>(comb, cWb, cellp);
  k_newmem<<<512, 256, 0, stream>>>(cellp, cell_b, memout, out_mem);
}

// Round 18
// 220.612 us; speedup vs baseline: 1.1368x; 1.0749x over previous
//
#include <hip/hip_runtime.h>
#include <hip/hip_bf16.h>

#define B_  2
#define S_  2048
#define M_  64
#define D_  1024
#define T_  2112      // M_ + S_
#define H_  16
#define HD_ 64
#define BT_ (B_*T_)   // 4224
#define NEGBIG (-1e9f)
#define LOG2E 1.44269504f

typedef float f32x4  __attribute__((ext_vector_type(4)));
typedef float f32x4b __attribute__((ext_vector_type(4)));
typedef short short8 __attribute__((ext_vector_type(8)));
typedef unsigned short u16x4 __attribute__((ext_vector_type(4)));
typedef __bf16 bf16x8 __attribute__((ext_vector_type(8)));

static __device__ __forceinline__ unsigned short bf16_of(float f) {
  __hip_bfloat16 h = __float2bfloat16(f);
  return __builtin_bit_cast(unsigned short, h);
}

static __device__ __forceinline__ f32x4 mfma_bf16(short8 a, short8 b, f32x4 c) {
  return __builtin_amdgcn_mfma_f32_16x16x32_bf16(
      __builtin_bit_cast(bf16x8, a), __builtin_bit_cast(bf16x8, b), c, 0, 0, 0);
}

// async global->LDS, 16B per lane; lds base must be wave-uniform (lane adds l*16).
static __device__ __forceinline__ void gload16(const void* g, void* lds) {
  __builtin_amdgcn_global_load_lds(
      (const __attribute__((address_space(1))) unsigned int*)g,
      (__attribute__((address_space(3))) unsigned int*)lds, 16, 0, 0);
}

// pack 8 f32 -> short8 of bf16
static __device__ __forceinline__ short8 pack8(const float* v, float scale) {
  short8 o;
#pragma unroll
  for (int k = 0; k < 8; k++) o[k] = (short)bf16_of(v[k] * scale);
  return o;
}

// ---------------- cast / concat kernels (vectorized) ----------------

__global__ void k_build_x(const float* __restrict__ tokens,
                          const float* __restrict__ memory,
                          unsigned short* __restrict__ xb) {
  const int NG = BT_ * D_ / 8;
  for (int gI = blockIdx.x * blockDim.x + threadIdx.x; gI < NG;
       gI += gridDim.x * blockDim.x) {
    int i = gI * 8;
    int b = (i >= T_ * D_) ? 1 : 0;
    int rem = i - b * (T_ * D_);
    int t = rem >> 10;            // D_ = 1024
    int d = rem & 1023;
    const float* src = (t < M_) ? &memory[(((size_t)b * M_ + t) << 10) + d]
                                : &tokens[(((size_t)b * S_ + (t - M_)) << 10) + d];
    float v[8];
    *(f32x4*)&v[0] = *(const f32x4*)&src[0];
    *(f32x4*)&v[4] = *(const f32x4*)&src[4];
    *(short8*)&xb[i] = pack8(v, 1.f);
  }
}

// casts: Wq,Wk,Wv -> contiguous Wqkvb (3x1M), Wo (1M), cell_W (4M), pool_q (64K scaled)
__global__ void k_cast_all(const float* __restrict__ Wq, const float* __restrict__ Wk,
                           const float* __restrict__ Wv, const float* __restrict__ Wo,
                           const float* __restrict__ cW, const float* __restrict__ pq,
                           unsigned short* __restrict__ Wqkvb, unsigned short* __restrict__ Wob,
                           unsigned short* __restrict__ cWb, unsigned short* __restrict__ pqb) {
  const int NW = D_ * D_;            // 1M
  const int NC = 4 * D_ * D_;        // 4M
  const int NP = M_ * D_;            // 64K
  const int NG = (4 * NW + NC + NP) / 8;
  for (int gI = blockIdx.x * blockDim.x + threadIdx.x; gI < NG;
       gI += gridDim.x * blockDim.x) {
    int i = gI * 8;
    const float* src;
    unsigned short* dst;
    float scale = 1.f;
    if (i < 3 * NW) {
      int which = i >> 20, j = i & (NW - 1);
      src = ((which == 0) ? Wq : (which == 1) ? Wk : Wv) + j;
      dst = Wqkvb + i;
    } else if (i < 4 * NW) {
      src = Wo + (i - 3 * NW);
      dst = Wob + (i - 3 * NW);
    } else if (i < 4 * NW + NC) {
      src = cW + (i - 4 * NW);
      dst = cWb + (i - 4 * NW);
    } else {
      src = pq + (i - 4 * NW - NC);
      dst = pqb + (i - 4 * NW - NC);
      scale = 0.03125f * LOG2E;      // D^-0.5, exp2-domain
    }
    float v[8];
    *(f32x4*)&v[0] = *(const f32x4*)&src[0];
    *(f32x4*)&v[4] = *(const f32x4*)&src[4];
    *(short8*)dst = pack8(v, scale);
  }
}

// ---------------- 128x128 GEMM core: dbuf BK=64, counted vmcnt (T4) ----------------
__device__ __forceinline__ void gemm128_core(const unsigned short* __restrict__ A,
                                             const unsigned short* __restrict__ BT,
                                             int K, int m0, int n0,
                                             f32x4 acc[4][4]) {
  __shared__ __align__(16) unsigned short As[2][128][64];
  __shared__ __align__(16) unsigned short Bs[2][128][64];
  const int tid = threadIdx.x;
  const int w = tid >> 6, l = tid & 63;
  const int wr = w >> 1, wc = w & 1;
  const int lr = l & 15, lg = l >> 4;
  f32x4 z; z[0] = z[1] = z[2] = z[3] = 0.f;
#pragma unroll
  for (int i = 0; i < 4; i++)
#pragma unroll
    for (int j = 0; j < 4; j++) acc[i][j] = z;

  auto stage = [&](int buf, int k0) {
#pragma unroll
    for (int c = 0; c < 4; c++) {
      int rbase = c * 32 + w * 8;
      int rr = rbase + (l >> 3);
      int u = (l & 7) ^ (rr & 7);
      gload16(&A[(size_t)(m0 + rr) * K + k0 + u * 8], &As[buf][rbase][0]);
      gload16(&BT[(size_t)(n0 + rr) * K + k0 + u * 8], &Bs[buf][rbase][0]);
    }
  };

  stage(0, 0);
  int cur = 0;
  const int NK = K >> 6;
  for (int kt = 0; kt < NK; kt++) {
    if (kt + 1 < NK) {
      stage(cur ^ 1, (kt + 1) << 6);
      asm volatile("s_waitcnt vmcnt(8)" ::: "memory");
    } else {
      asm volatile("s_waitcnt vmcnt(0)" ::: "memory");
    }
    __builtin_amdgcn_s_barrier();

    short8 a[4][2], b[4][2];
#pragma unroll
    for (int i = 0; i < 4; i++) {
      int row = wr * 64 + i * 16 + lr;
      int sw = row & 7;
#pragma unroll
      for (int kk = 0; kk < 2; kk++)
        a[i][kk] = *(const short8*)&As[cur][row][(((kk << 2) | lg) ^ sw) * 8];
    }
#pragma unroll
    for (int j = 0; j < 4; j++) {
      int row = wc * 64 + j * 16 + lr;
      int sw = row & 7;
#pragma unroll
      for (int kk = 0; kk < 2; kk++)
        b[j][kk] = *(const short8*)&Bs[cur][row][(((kk << 2) | lg) ^ sw) * 8];
    }
    __builtin_amdgcn_s_setprio(1);
#pragma unroll
    for (int kk = 0; kk < 2; kk++)
#pragma unroll
      for (int i = 0; i < 4; i++)
#pragma unroll
        for (int j = 0; j < 4; j++)
          acc[i][j] = mfma_bf16(a[i][kk], b[j][kk], acc[i][j]);
    __builtin_amdgcn_s_setprio(0);

    __builtin_amdgcn_s_barrier();
    cur ^= 1;
  }
}

// ---------------- small 64x64 GEMM core (partial-K capable) ----------------
__device__ __forceinline__ void gemm_core(const unsigned short* __restrict__ A,
                                          const unsigned short* __restrict__ BT,
                                          int ldk, int Klen, int m0, int n0,
                                          f32x4 acc[4]) {
  __shared__ __align__(16) unsigned short As[64][40];
  __shared__ __align__(16) unsigned short Bs[64][40];
  const int tid = threadIdx.x;
  const int w = tid >> 6, l = tid & 63;
  const int sr = tid >> 2, sc = (tid & 3) * 8;
  f32x4 z; z[0] = z[1] = z[2] = z[3] = 0.f;
  acc[0] = acc[1] = acc[2] = acc[3] = z;
  for (int k0 = 0; k0 < Klen; k0 += 32) {
    __syncthreads();
    *(short8*)&As[sr][sc] = *(const short8*)&A[(size_t)(m0 + sr) * ldk + k0 + sc];
    *(short8*)&Bs[sr][sc] = *(const short8*)&BT[(size_t)(n0 + sr) * ldk + k0 + sc];
    __syncthreads();
    short8 a = *(const short8*)&As[w * 16 + (l & 15)][(l >> 4) * 8];
#pragma unroll
    for (int n = 0; n < 4; n++) {
      short8 b = *(const short8*)&Bs[n * 16 + (l & 15)][(l >> 4) * 8];
      acc[n] = mfma_bf16(a, b, acc[n]);
    }
  }
}

// ---------------- fused QKV projection (128-tile, XCD-chunked grid) ----------------
// flat grid 792.  xcd = id&7, s = id>>3, g = xcd*99 + s (bijective);
// mt = g/24 (m-panel), nn = g%24 (which = nn>>3, n-tile = nn&7).
// Each XCD owns ~4 consecutive m-panels for ALL n-tiles -> xb panel stays in
// its private L2 instead of being fetched by all 8 XCDs.
__global__ __launch_bounds__(256) void k_qkv(
    const unsigned short* __restrict__ xb, const unsigned short* __restrict__ Wqkvb,
    const float* __restrict__ bq, const float* __restrict__ bk,
    const float* __restrict__ bv, unsigned short* __restrict__ qg,
    unsigned short* __restrict__ kg, unsigned short* __restrict__ vTg) {
  const int id = blockIdx.x;
  const int xcd = id & 7;
  const int g = xcd * 99 + (id >> 3);
  const int mt = g / 24, nn = g - mt * 24;
  const int which = nn >> 3;
  const unsigned short* W = Wqkvb + (size_t)which * D_ * D_;
  const float* bias = (which == 0) ? bq : ((which == 1) ? bk : bv);
  f32x4 acc[4][4];
  const int m0 = mt * 128, n0 = (nn & 7) * 128;
  gemm128_core(xb, W, D_, m0, n0, acc);
  const int tid = threadIdx.x, w = tid >> 6, l = tid & 63;
  const int wr = w >> 1, wc = w & 1;
#pragma unroll
  for (int i = 0; i < 4; i++) {
#pragma unroll
    for (int j = 0; j < 4; j++) {
#pragma unroll
      for (int r = 0; r < 4; r++) {
        int m = m0 + wr * 64 + i * 16 + (l >> 4) * 4 + r;
        int c = n0 + wc * 64 + j * 16 + (l & 15);
        int b = (m >= T_) ? 1 : 0;           // B_=2: single boundary compare
        int t = m - b * T_;
        int h = c >> 6, dh = c & 63;
        int bh = b * H_ + h;
        float v = acc[i][j][r] + bias[c];
        if (which == 0)
          qg[((size_t)bh * T_ + t) * HD_ + dh] = bf16_of(v * 0.125f * LOG2E);
        else if (which == 1)
          kg[((size_t)bh * T_ + t) * HD_ + dh] = bf16_of(v);
        else
          vTg[((size_t)bh * HD_ + dh) * T_ + t] = bf16_of(v);
      }
    }
  }
}

// ---------------- fused attention (R8 structure: K/V dbuf, 1 sync/iter) ----------------
// grid: 1056 blocks.  id = 8*((bh/8)*33 + qtr) + bh%8; qt = qtr==0 ? 0 : 33-qtr.
// Block = 4 waves, 64 q-rows; wave w owns rows [qt*64 + w*16, +16).
__global__ __launch_bounds__(256) void k_attn(
    const unsigned short* __restrict__ qg, const unsigned short* __restrict__ kg,
    const unsigned short* __restrict__ vTg, unsigned short* __restrict__ ctx) {
  const int id = blockIdx.x;
  const int xcd = id & 7;
  const int rem = id >> 3;
  const int g = rem / 33, qtr = rem - g * 33;
  const int qt = (qtr == 0) ? 0 : 33 - qtr;
  const int bh = g * 8 + xcd;
  const int tid = threadIdx.x, w = tid >> 6, l = tid & 63;
  const int lr = l & 15, lg = l >> 4;
  __shared__ __align__(16) unsigned short Ks[2][64][64];
  __shared__ __align__(16) unsigned short Vs[2][64][64];
  __shared__ __align__(16) unsigned short Ps[4][16][72];

  const unsigned short* qb = qg + (size_t)bh * T_ * HD_;
  const unsigned short* kb = kg + (size_t)bh * T_ * HD_;
  const unsigned short* vb = vTg + (size_t)bh * HD_ * T_;

  short8 aq[2];
  const int qrow = qt * 64 + w * 16 + lr;
#pragma unroll
  for (int st = 0; st < 2; st++)
    aq[st] = *(const short8*)&qb[(size_t)qrow * HD_ + st * 32 + lg * 8];

  f32x4 zz; zz[0] = zz[1] = zz[2] = zz[3] = 0.f;
  f32x4 o[4];
  o[0] = o[1] = o[2] = o[3] = zz;
  float mrun = -1e30f, lrun = 0.f;

  const int nkt = (qt == 0) ? 33 : qt + 1;

  auto stage = [&](int buf, int kb2) {
#pragma unroll
    for (int i = 0; i < 2; i++) {
      int rr = w * 16 + i * 8 + (l >> 3);
      int swz = ((l & 7) ^ (rr & 7)) * 8;
      gload16(&kb[(size_t)(kb2 + rr) * HD_ + swz], &Ks[buf][w * 16 + i * 8][0]);
      gload16(&vb[(size_t)rr * T_ + kb2 + swz], &Vs[buf][w * 16 + i * 8][0]);
    }
  };

  stage(0, 0);
  __syncthreads();
  int cur = 0;

  for (int j = 0; j < nkt; j++) {
    const int kbase = j * 64;
    if (j + 1 < nkt) stage(cur ^ 1, kbase + 64);

    short8 bkf[2][4];
#pragma unroll
    for (int n = 0; n < 4; n++) {
      int row = n * 16 + lr;
      int sw = lr & 7;
#pragma unroll
      for (int st = 0; st < 2; st++)
        bkf[st][n] = *(const short8*)&Ks[cur][row][((st * 4 + lg) ^ sw) * 8];
    }
    f32x4 s[4];
    s[0] = s[1] = s[2] = s[3] = zz;
    __builtin_amdgcn_s_setprio(1);
#pragma unroll
    for (int st = 0; st < 2; st++)
#pragma unroll
      for (int n = 0; n < 4; n++)
        s[n] = mfma_bf16(bkf[st][n], aq[st], s[n]);
    __builtin_amdgcn_s_setprio(0);

    if (qt > 0 && j == qt) {
      const int tql = w * 16 + lr;
#pragma unroll
      for (int n = 0; n < 4; n++)
#pragma unroll
        for (int r = 0; r < 4; r++) {
          int tkl = n * 16 + lg * 4 + r;
          if (tkl > tql) s[n][r] = NEGBIG;
        }
    }
    float pm = s[0][0];
#pragma unroll
    for (int n = 0; n < 4; n++)
#pragma unroll
      for (int r = 0; r < 4; r++) pm = fmaxf(pm, s[n][r]);
    pm = fmaxf(pm, __shfl_xor(pm, 16));
    pm = fmaxf(pm, __shfl_xor(pm, 32));

    if (__any(pm > mrun + 8.f)) {
      float mn = fmaxf(mrun, pm);
      float fac = exp2f(mrun - mn);
      mrun = mn;
      lrun *= fac;
      float fr[4];
#pragma unroll
      for (int r = 0; r < 4; r++) fr[r] = __shfl(fac, lg * 4 + r);
#pragma unroll
      for (int n = 0; n < 4; n++)
#pragma unroll
        for (int r = 0; r < 4; r++) o[n][r] *= fr[r];
    }
#pragma unroll
    for (int n = 0; n < 4; n++) {
      u16x4 pk;
#pragma unroll
      for (int r = 0; r < 4; r++) {
        float p = exp2f(s[n][r] - mrun);
        lrun += p;
        pk[r] = bf16_of(p);
      }
      *(u16x4*)&Ps[w][lr][n * 16 + lg * 4] = pk;
    }

    short8 bvf[2][4];
#pragma unroll
    for (int n = 0; n < 4; n++) {
      int row = n * 16 + lr;
      int sw = lr & 7;
#pragma unroll
      for (int st = 0; st < 2; st++)
        bvf[st][n] = *(const short8*)&Vs[cur][row][((st * 4 + lg) ^ sw) * 8];
    }
    short8 ap[2];
#pragma unroll
    for (int st = 0; st < 2; st++)
      ap[st] = *(const short8*)&Ps[w][lr][st * 32 + lg * 8];
    __builtin_amdgcn_s_setprio(1);
#pragma unroll
    for (int st = 0; st < 2; st++)
#pragma unroll
      for (int n = 0; n < 4; n++)
        o[n] = mfma_bf16(ap[st], bvf[st][n], o[n]);
    __builtin_amdgcn_s_setprio(0);

    __syncthreads();
    cur ^= 1;
  }
  lrun += __shfl_xor(lrun, 16);
  lrun += __shfl_xor(lrun, 32);
  float linv[4];
#pragma unroll
  for (int r = 0; r < 4; r++) linv[r] = 1.f / __shfl(lrun, lg * 4 + r);

  const int b = bh >> 4, h = bh & 15;
#pragma unroll
  for (int n = 0; n < 4; n++)
#pragma unroll
    for (int r = 0; r < 4; r++) {
      int tq = qt * 64 + w * 16 + lg * 4 + r;
      float val = o[n][r] * linv[r];
      ctx[((size_t)(b * T_ + tq)) * D_ + h * HD_ + n * 16 + lr] = bf16_of(val);
    }
}

// ---------------- output projection + residual + splits (128-tile) ----------------
__global__ __launch_bounds__(256) void k_out(
    const unsigned short* __restrict__ ctxb, const unsigned short* __restrict__ Wob,
    const float* __restrict__ bo, const float* __restrict__ tokens,
    const float* __restrict__ memory, float* __restrict__ out_tok,
    unsigned short* __restrict__ tokb, unsigned short* __restrict__ tokTb,
    float* __restrict__ memout, unsigned short* __restrict__ comb) {
  f32x4 acc[4][4];
  const int m0 = blockIdx.y * 128, n0 = blockIdx.x * 128;
  gemm128_core(ctxb, Wob, D_, m0, n0, acc);
  const int tid = threadIdx.x, w = tid >> 6, l = tid & 63;
  const int wr = w >> 1, wc = w & 1;
#pragma unroll
  for (int i = 0; i < 4; i++) {
#pragma unroll
    for (int j = 0; j < 4; j++) {
#pragma unroll
      for (int r = 0; r < 4; r++) {
        int m = m0 + wr * 64 + i * 16 + (l >> 4) * 4 + r;
        int c = n0 + wc * 64 + j * 16 + (l & 15);
        int b = (m >= T_) ? 1 : 0;
        int t = m - b * T_;
        float xo = (t < M_) ? memory[((size_t)b * M_ + t) * D_ + c]
                            : tokens[((size_t)b * S_ + (t - M_)) * D_ + c];
        float val = acc[i][j][r] + bo[c] + xo;
        if (t < M_) {
          memout[((size_t)b * M_ + t) * D_ + c] = val;
          comb[((size_t)b * M_ + t) * (2 * D_) + c] = bf16_of(val);
        } else {
          size_t ti = (size_t)b * S_ + (t - M_);
          out_tok[ti * D_ + c] = val;
          tokb[ti * D_ + c] = bf16_of(val);
          tokTb[((size_t)b * D_ + c) * S_ + (t - M_)] = bf16_of(val);
        }
      }
    }
  }
}

// ---------------- pool scores: split-K partials ----------------
__global__ __launch_bounds__(256) void k_pscore_part(
    const unsigned short* __restrict__ pqb, const unsigned short* __restrict__ tokb,
    float* __restrict__ pscp) {
  const int stile = blockIdx.x, ks = blockIdx.y, b = blockIdx.z;
  f32x4 acc[4];
  gemm_core(pqb + ks * 256, tokb + (size_t)b * S_ * D_ + ks * 256, D_, 256,
            0, stile * 64, acc);
  const int tid = threadIdx.x, w = tid >> 6, l = tid & 63;
  float* dst = pscp + ((size_t)(ks * B_ + b) * M_) * S_;
#pragma unroll
  for (int n = 0; n < 4; n++) {
#pragma unroll
    for (int r = 0; r < 4; r++) {
      int m = w * 16 + (l >> 4) * 4 + r;
      int s = stile * 64 + n * 16 + (l & 15);
      dst[(size_t)m * S_ + s] = acc[n][r];
    }
  }
}

// ---------------- pool softmax (sums 4 partials; exp2 domain) ----------------
__global__ __launch_bounds__(256) void k_psoftmax(const float* __restrict__ pscp,
                                                  unsigned short* __restrict__ pw) {
  const int row = blockIdx.x;          // b*64 + m
  const int b = row >> 6, m = row & 63;
  const int tid = threadIdx.x;
  float v[8];
  float mx = -1e30f;
#pragma unroll
  for (int i = 0; i < 8; i++) {
    int s = tid + i * 256;
    float acc = 0.f;
#pragma unroll
    for (int ks = 0; ks < 4; ks++)
      acc += pscp[((size_t)(ks * B_ + b) * M_ + m) * S_ + s];
    v[i] = acc;
    mx = fmaxf(mx, acc);
  }
#pragma unroll
  for (int off = 1; off < 64; off <<= 1) mx = fmaxf(mx, __shfl_xor(mx, off));
  __shared__ float rm[4], rs[4];
  if ((tid & 63) == 0) rm[tid >> 6] = mx;
  __syncthreads();
  mx = fmaxf(fmaxf(rm[0], rm[1]), fmaxf(rm[2], rm[3]));
  float sum = 0.f;
#pragma unroll
  for (int i = 0; i < 8; i++) {
    v[i] = exp2f(v[i] - mx);
    sum += v[i];
  }
#pragma unroll
  for (int off = 1; off < 64; off <<= 1) sum += __shfl_xor(sum, off);
  if ((tid & 63) == 0) rs[tid >> 6] = sum;
  __syncthreads();
  float inv = 1.f / (rs[0] + rs[1] + rs[2] + rs[3]);
#pragma unroll
  for (int i = 0; i < 8; i++)
    pw[(size_t)row * S_ + tid + i * 256] = bf16_of(v[i] * inv);
}

// ---------------- summary: split-K partials ----------------
__global__ __launch_bounds__(256) void k_summary_part(
    const unsigned short* __restrict__ pw, const unsigned short* __restrict__ tokTb,
    float* __restrict__ sump) {
  const int nt = blockIdx.x, ks = blockIdx.y, b = blockIdx.z;
  f32x4 acc[4];
  gemm_core(pw + (size_t)b * M_ * S_ + ks * 256,
            tokTb + (size_t)b * D_ * S_ + ks * 256, S_, 256, 0, nt * 64, acc);
  const int tid = threadIdx.x, w = tid >> 6, l = tid & 63;
  float* dst = sump + ((size_t)(ks * B_ + b) * M_) * D_;
#pragma unroll
  for (int n = 0; n < 4; n++) {
#pragma unroll
    for (int r = 0; r < 4; r++) {
      int m = w * 16 + (l >> 4) * 4 + r;
      int c = nt * 64 + n * 16 + (l & 15);
      dst[(size_t)m * D_ + c] = acc[n][r];
    }
  }
}

// combine summary partials -> comb[:, D_:]
__global__ void k_sumcomb(const float* __restrict__ sump,
                          unsigned short* __restrict__ comb) {
  int i = blockIdx.x * blockDim.x + threadIdx.x;
  if (i >= B_ * M_ * D_) return;
  int bm = i >> 10, c = i & 1023;
  int b = bm >> 6, m = bm & 63;
  float acc = 0.f;
#pragma unroll
  for (int ks = 0; ks < 8; ks++)
    acc += sump[((size_t)(ks * B_ + b) * M_ + m) * D_ + c];
  comb[((size_t)b * M_ + m) * (2 * D_) + D_ + c] = bf16_of(acc);
}

// ---------------- cell GEMM: split-K partials ----------------
__global__ __launch_bounds__(256) void k_cell_part(
    const unsigned short* __restrict__ comb, const unsigned short* __restrict__ cWb,
    float* __restrict__ cellp) {
  const int nt = blockIdx.x, mt = blockIdx.y, ks = blockIdx.z;
  f32x4 acc[4];
  gemm_core(comb + ks * 512, cWb + ks * 512, 2 * D_, 512, mt * 64, nt * 64, acc);
  const int tid = threadIdx.x, w = tid >> 6, l = tid & 63;
#pragma unroll
  for (int n = 0; n < 4; n++) {
#pragma unroll
    for (int r = 0; r < 4; r++) {
      int m = mt * 64 + w * 16 + (l >> 4) * 4 + r;
      int c = nt * 64 + n * 16 + (l & 15);
      cellp[((size_t)ks * (B_ * M_) + m) * (2 * D_) + c] = acc[n][r];
    }
  }
}

// ---------------- final gating (sums 4 cell partials + bias) ----------------
__global__ void k_newmem(const float* __restrict__ cellp,
                         const float* __restrict__ cb,
                         const float* __restrict__ memout,
                         float* __restrict__ out2) {
  int i = blockIdx.x * blockDim.x + threadIdx.x;
  if (i >= B_ * M_ * D_) return;
  int r = i >> 10, d = i & 1023;
  float gsum = cb[d], csum = cb[D_ + d];
#pragma unroll
  for (int ks = 0; ks < 4; ks++) {
    gsum += cellp[((size_t)ks * (B_ * M_) + r) * (2 * D_) + d];
    csum += cellp[((size_t)ks * (B_ * M_) + r) * (2 * D_) + D_ + d];
  }
  float sg = 1.f / (1.f + __expf(-gsum));
  float sc = 1.f / (1.f + __expf(-csum));
  out2[i] = memout[i] * sg + (1.f - sg) * (csum * sc);
}

// ---------------- launch ----------------
extern "C" void kernel_launch(void* const* d_in, const int* in_sizes, int n_in,
                              void* d_out, int out_size, void* d_ws, size_t ws_size,
                              hipStream_t stream) {
  const float* tokens = (const float*)d_in[0];
  const float* memory = (const float*)d_in[1];
  const float* Wq = (const float*)d_in[2];
  const float* bq = (const float*)d_in[3];
  const float* Wk = (const float*)d_in[4];
  const float* bk = (const float*)d_in[5];
  const float* Wv = (const float*)d_in[6];
  const float* bv = (const float*)d_in[7];
  const float* Wo = (const float*)d_in[8];
  const float* bo = (const float*)d_in[9];
  const float* pool_q = (const float*)d_in[10];
  const float* cell_W = (const float*)d_in[11];
  const float* cell_b = (const float*)d_in[12];

  size_t off = 0;
  auto alloc = [&](size_t bytes) -> void* {
    void* p = (char*)d_ws + off;
    off += (bytes + 255) & ~(size_t)255;
    return p;
  };
  unsigned short* xb    = (unsigned short*)alloc((size_t)BT_ * D_ * 2);
  unsigned short* Wqkvb = (unsigned short*)alloc((size_t)3 * D_ * D_ * 2);
  unsigned short* Wob   = (unsigned short*)alloc((size_t)D_ * D_ * 2);
  unsigned short* cWb   = (unsigned short*)alloc((size_t)(2 * D_) * (2 * D_) * 2);
  unsigned short* pqb   = (unsigned short*)alloc((size_t)M_ * D_ * 2);
  unsigned short* qg    = (unsigned short*)alloc((size_t)B_ * H_ * T_ * HD_ * 2);
  unsigned short* kg    = (unsigned short*)alloc((size_t)B_ * H_ * T_ * HD_ * 2);
  unsigned short* vTg   = (unsigned short*)alloc((size_t)B_ * H_ * HD_ * T_ * 2);
  unsigned short* ctxb  = (unsigned short*)alloc((size_t)BT_ * D_ * 2);
  unsigned short* tokb  = (unsigned short*)alloc((size_t)B_ * S_ * D_ * 2);
  unsigned short* tokTb = (unsigned short*)alloc((size_t)B_ * D_ * S_ * 2);
  float*          memout= (float*)alloc((size_t)B_ * M_ * D_ * 4);
  unsigned short* comb  = (unsigned short*)alloc((size_t)B_ * M_ * 2 * D_ * 2);
  unsigned short* pwt   = (unsigned short*)alloc((size_t)B_ * M_ * S_ * 2);
  float*          pscp  = (float*)alloc((size_t)4 * B_ * M_ * S_ * 4);
  float*          sump  = (float*)alloc((size_t)8 * B_ * M_ * D_ * 4);
  float*          cellp = (float*)alloc((size_t)4 * B_ * M_ * 2 * D_ * 4);

  float* out_tok = (float*)d_out;
  float* out_mem = out_tok + (size_t)B_ * S_ * D_;

  k_build_x<<<2048, 256, 0, stream>>>(tokens, memory, xb);
  k_cast_all<<<2048, 256, 0, stream>>>(Wq, Wk, Wv, Wo, cell_W, pool_q,
                                       Wqkvb, Wob, cWb, pqb);

  k_qkv<<<792, 256, 0, stream>>>(xb, Wqkvb, bq, bk, bv, qg, kg, vTg);
  k_attn<<<1056, 256, 0, stream>>>(qg, kg, vTg, ctxb);
  k_out<<<dim3(8, 33), 256, 0, stream>>>(ctxb, Wob, bo, tokens, memory, out_tok,
                                         tokb, tokTb, memout, comb);
  k_pscore_part<<<dim3(32, 4, 2), 256, 0, stream>>>(pqb, tokb, pscp);
  k_psoftmax<<<B_ * M_, 256, 0, stream>>>(pscp, pwt);
  k_summary_part<<<dim3(16, 8, 2), 256, 0, stream>>>(pwt, tokTb, sump);
  k_sumcomb<<<512, 256, 0, stream>>>(sump, comb);
  k_cell_part<<<dim3(32, 2, 4), 256, 0, stream>>>(comb, cWb, cellp);
  k_newmem<<<512, 256, 0, stream>>>(cellp, cell_b, memout, out_mem);
}